// Round 1
// baseline (1491.538 us; speedup 1.0000x reference)
//
#include <hip/hip_runtime.h>
#include <math.h>

#define NIMG 16
#define A 3
#define HH 256
#define WW 256
#define HW 65536
#define AHW 196608
#define PRE 2000
#define POST 1000
#define CAP 8192
#define NBUCKET 2048
#define NEGF (-1e30f)

__device__ __forceinline__ unsigned mapf(float x) {
    unsigned u = __float_as_uint(x);
    return (u & 0x80000000u) ? ~u : (u | 0x80000000u);
}

// K1: per-image histogram of top 11 bits of monotone-mapped objectness
__global__ void k_hist(const float* __restrict__ obj, unsigned* __restrict__ hist) {
    __shared__ unsigned lh[NBUCKET];
    int img = blockIdx.y;
    for (int i = threadIdx.x; i < NBUCKET; i += blockDim.x) lh[i] = 0;
    __syncthreads();
    const float* p = obj + (size_t)img * AHW;
    int stride = gridDim.x * blockDim.x;
    for (int i = blockIdx.x * blockDim.x + threadIdx.x; i < AHW; i += stride) {
        unsigned m = mapf(p[i]);
        atomicAdd(&lh[m >> 21], 1u);
    }
    __syncthreads();
    unsigned* gh = hist + img * NBUCKET;
    for (int i = threadIdx.x; i < NBUCKET; i += blockDim.x)
        if (lh[i]) atomicAdd(&gh[i], lh[i]);
}

// K2: find threshold bucket B per image (cumulative from top >= PRE)
__global__ void k_thresh(const unsigned* __restrict__ hist, unsigned* __restrict__ bsel) {
    int img = blockIdx.x * blockDim.x + threadIdx.x;
    if (img >= NIMG) return;
    const unsigned* gh = hist + img * NBUCKET;
    unsigned cum = 0; int b = 0;
    for (int i = NBUCKET - 1; i >= 0; --i) {
        cum += gh[i];
        if (cum >= PRE) { b = i; break; }
    }
    bsel[img] = (unsigned)b;
}

// K3: compact all candidates with bucket >= B into keys array
__global__ void k_compact(const float* __restrict__ obj, const unsigned* __restrict__ bsel,
                          unsigned* __restrict__ selcnt, unsigned long long* __restrict__ keys) {
    int img = blockIdx.y;
    unsigned thr = bsel[img] << 21;
    const float* p = obj + (size_t)img * AHW;
    int stride = gridDim.x * blockDim.x;
    for (int j = blockIdx.x * blockDim.x + threadIdx.x; j < AHW; j += stride) {
        unsigned m = mapf(p[j]);
        if (m >= thr) {
            int a = j >> 16;          // j = a*HW + hw  (objectness layout N,A,H,W)
            int hw = j & 65535;
            unsigned idx = (unsigned)(hw * A + a);  // candidate index in (h,w,a) order
            unsigned pos = atomicAdd(&selcnt[img], 1u);
            if (pos < CAP)
                keys[(size_t)img * CAP + pos] =
                    ((unsigned long long)m << 32) | (unsigned)(~idx);
        }
    }
}

// K4: per-image bitonic sort of CAP keys, descending; first PRE written back
__global__ void __launch_bounds__(512) k_sort(unsigned long long* __restrict__ keys) {
    __shared__ unsigned long long s[CAP];
    int img = blockIdx.x;
    unsigned long long* g = keys + (size_t)img * CAP;
    for (int i = threadIdx.x; i < CAP; i += blockDim.x) s[i] = g[i];
    __syncthreads();
    for (int k2 = 2; k2 <= CAP; k2 <<= 1) {
        for (int j = k2 >> 1; j > 0; j >>= 1) {
            for (int t = threadIdx.x; t < CAP; t += blockDim.x) {
                int ixj = t ^ j;
                if (ixj > t) {
                    unsigned long long a = s[t], b = s[ixj];
                    bool up = ((t & k2) == 0);
                    if (up ? (a < b) : (a > b)) { s[t] = b; s[ixj] = a; }
                }
            }
            __syncthreads();
        }
    }
    for (int i = threadIdx.x; i < PRE; i += blockDim.x) g[i] = s[i];
}

// K5: decode boxes (f64), clip, MIN_SIZE filter, sigmoid score
__global__ void k_decode(const float* __restrict__ anchors, const float* __restrict__ br,
                         const unsigned long long* __restrict__ keys,
                         double* __restrict__ boxes, float* __restrict__ scores,
                         unsigned* __restrict__ negmask) {
    int g = blockIdx.x * blockDim.x + threadIdx.x;
    if (g >= NIMG * PRE) return;
    int img = g / PRE, r = g % PRE;
    unsigned long long key = keys[(size_t)img * CAP + r];
    unsigned m = (unsigned)(key >> 32);
    unsigned idx = ~(unsigned)key;
    unsigned u = (m & 0x80000000u) ? (m ^ 0x80000000u) : ~m;
    float x = __uint_as_float(u);
    double sc = 1.0 / (1.0 + exp(-(double)x));
    int a = idx % 3;
    int hw = idx / 3;
    const float* anc = anchors + ((size_t)img * AHW + idx) * 4;
    double ax1 = anc[0], ay1 = anc[1], ax2 = anc[2], ay2 = anc[3];
    double aw = ax2 - ax1 + 1.0, ah = ay2 - ay1 + 1.0;
    double cx = ax1 + 0.5 * aw, cy = ay1 + 0.5 * ah;
    const float* bp = br + (size_t)img * 12 * HW + (size_t)a * 4 * HW + hw;
    double dx = bp[0];
    double dy = bp[(size_t)HW];
    double dw = bp[(size_t)2 * HW];
    double dh = bp[(size_t)3 * HW];
    const double CLIPV = 4.135166556742356; // log(1000/16)
    dw = fmin(dw, CLIPV); dh = fmin(dh, CLIPV);
    double pcx = dx * aw + cx, pcy = dy * ah + cy;
    double pw = exp(dw) * aw, ph = exp(dh) * ah;
    double x1 = pcx - 0.5 * pw, y1 = pcy - 0.5 * ph;
    double x2 = pcx + 0.5 * pw - 1.0, y2 = pcy + 0.5 * ph - 1.0;
    x1 = fmin(fmax(x1, 0.0), 1023.0);
    y1 = fmin(fmax(y1, 0.0), 1023.0);
    x2 = fmin(fmax(x2, 0.0), 1023.0);
    y2 = fmin(fmax(y2, 0.0), 1023.0);
    bool keep = (x2 - x1 + 1.0 >= 0.0) && (y2 - y1 + 1.0 >= 0.0);
    double* bo = boxes + ((size_t)img * PRE + r) * 4;
    bo[0] = x1; bo[1] = y1; bo[2] = x2; bo[3] = y2;
    scores[img * PRE + r] = keep ? (float)sc : NEGF;
    if (!keep) atomicOr(&negmask[img * 64 + (r >> 5)], 1u << (r & 31));
}

// K6: IoU suppression bitmask: mask[img][r][word] bit j -> iou(r, r-block col j) > 0.7
__global__ void k_mask(const double* __restrict__ boxes, unsigned* __restrict__ mask) {
    int img = blockIdx.y;
    int r = blockIdx.x;
    int t = threadIdx.x; // 0..63
    const double* base = boxes + (size_t)img * PRE * 4;
    const double* brow = base + (size_t)r * 4;
    double x1 = brow[0], y1 = brow[1], x2 = brow[2], y2 = brow[3];
    double area_r = (x2 - x1 + 1.0) * (y2 - y1 + 1.0);
    unsigned bits = 0;
    int j0 = t * 32;
    for (int jj = 0; jj < 32; ++jj) {
        int j = j0 + jj;
        if (j >= PRE) break;
        const double* bj = base + (size_t)j * 4;
        double bx1 = bj[0], by1 = bj[1], bx2 = bj[2], by2 = bj[3];
        double iw = fmin(x2, bx2) - fmax(x1, bx1) + 1.0;
        double ih = fmin(y2, by2) - fmax(y1, by1) + 1.0;
        if (iw > 0.0 && ih > 0.0) {
            double inter = iw * ih;
            double areaj = (bx2 - bx1 + 1.0) * (by2 - by1 + 1.0);
            double iou = inter / (area_r + areaj - inter);
            if (iou > 0.7) bits |= (1u << jj);
        }
    }
    mask[((size_t)img * PRE + r) * 64 + t] = bits;
}

// K7: greedy serial NMS scan using suppression bitmask
__global__ void __launch_bounds__(64) k_nms(const double* __restrict__ boxes,
                                            const float* __restrict__ scores,
                                            const unsigned* __restrict__ negmask,
                                            const unsigned* __restrict__ mask,
                                            float* __restrict__ out) {
    __shared__ unsigned sup[64];
    __shared__ int pick;
    int img = blockIdx.x;
    int t = threadIdx.x;
    unsigned sm = negmask[img * 64 + t];
    if (t == 62) sm |= 0xFFFF0000u;  // indices 2000..2015 invalid
    if (t == 63) sm = 0xFFFFFFFFu;   // indices 2016..2047 invalid
    sup[t] = sm;
    __syncthreads();
    float* ob = out + (size_t)img * POST * 4;
    float* os = out + (size_t)NIMG * POST * 4 + (size_t)img * POST;
    int head = 0;
    int o = 0;
    for (; o < POST; ++o) {
        if (t == 0) {
            int p = -1;
            int wstart = head >> 5;
            for (int w2 = wstart; w2 < 64; ++w2) {
                unsigned v = ~sup[w2];
                if (w2 == wstart) v &= (0xFFFFFFFFu << (head & 31));
                if (v) { p = (w2 << 5) + __ffs(v) - 1; break; }
            }
            pick = p;
        }
        __syncthreads();
        int p = pick;
        if (p < 0) break;
        const unsigned* mrow = mask + ((size_t)img * PRE + p) * 64;
        sup[t] |= mrow[t];
        if (t < 4) ob[o * 4 + t] = (float)boxes[((size_t)img * PRE + p) * 4 + t];
        if (t == 4) os[o] = scores[img * PRE + p];
        head = p + 1;
        __syncthreads();
    }
    for (int k = o; k < POST; ++k) {
        if (t < 4) ob[k * 4 + t] = 0.0f;
        if (t == 4) os[k] = NEGF;
    }
}

extern "C" void kernel_launch(void* const* d_in, const int* in_sizes, int n_in,
                              void* d_out, int out_size, void* d_ws, size_t ws_size,
                              hipStream_t stream) {
    const float* anchors = (const float*)d_in[0];
    const float* obj = (const float*)d_in[1];
    const float* br = (const float*)d_in[2];
    float* out = (float*)d_out;

    char* ws = (char*)d_ws;
    size_t off = 0;
    auto alloc = [&](size_t bytes) {
        void* p = ws + off;
        off = (off + bytes + 255) & ~(size_t)255;
        return p;
    };
    unsigned* hist = (unsigned*)alloc((size_t)NIMG * NBUCKET * 4);
    unsigned* bsel = (unsigned*)alloc(NIMG * 4);
    unsigned* selcnt = (unsigned*)alloc(NIMG * 4);
    unsigned long long* keys = (unsigned long long*)alloc((size_t)NIMG * CAP * 8);
    double* boxes = (double*)alloc((size_t)NIMG * PRE * 4 * 8);
    float* scores = (float*)alloc((size_t)NIMG * PRE * 4);
    unsigned* negmask = (unsigned*)alloc((size_t)NIMG * 64 * 4);
    unsigned* mask = (unsigned*)alloc((size_t)NIMG * PRE * 64 * 4);

    hipMemsetAsync(hist, 0, (size_t)NIMG * NBUCKET * 4, stream);
    hipMemsetAsync(selcnt, 0, (size_t)NIMG * 4, stream);
    hipMemsetAsync(keys, 0, (size_t)NIMG * CAP * 8, stream);
    hipMemsetAsync(negmask, 0, (size_t)NIMG * 64 * 4, stream);

    k_hist<<<dim3(64, NIMG), 256, 0, stream>>>(obj, hist);
    k_thresh<<<1, NIMG, 0, stream>>>(hist, bsel);
    k_compact<<<dim3(64, NIMG), 256, 0, stream>>>(obj, bsel, selcnt, keys);
    k_sort<<<NIMG, 512, 0, stream>>>(keys);
    k_decode<<<(NIMG * PRE + 255) / 256, 256, 0, stream>>>(anchors, br, keys, boxes, scores, negmask);
    k_mask<<<dim3(PRE, NIMG), 64, 0, stream>>>(boxes, mask);
    k_nms<<<NIMG, 64, 0, stream>>>(boxes, scores, negmask, mask, out);
}

// Round 2
// 1214.437 us; speedup vs baseline: 1.2282x; 1.2282x over previous
//
#include <hip/hip_runtime.h>
#include <math.h>

#define NIMG 16
#define A 3
#define HH 256
#define WW 256
#define HW 65536
#define AHW 196608
#define PRE 2000
#define POST 1000
#define CAP2 4096
#define NBUCKET 2048
#define NEGF (-1e30f)
#define TILE_R 8

__device__ __forceinline__ unsigned mapf(float x) {
    unsigned u = __float_as_uint(x);
    return (u & 0x80000000u) ? ~u : (u | 0x80000000u);
}

// K1: per-image histogram of top 11 bits of monotone-mapped objectness
__global__ void k_hist(const float* __restrict__ obj, unsigned* __restrict__ hist) {
    __shared__ unsigned lh[NBUCKET];
    int img = blockIdx.y;
    for (int i = threadIdx.x; i < NBUCKET; i += blockDim.x) lh[i] = 0;
    __syncthreads();
    const float* p = obj + (size_t)img * AHW;
    int stride = gridDim.x * blockDim.x;
    for (int i = blockIdx.x * blockDim.x + threadIdx.x; i < AHW; i += stride) {
        unsigned m = mapf(p[i]);
        atomicAdd(&lh[m >> 21], 1u);
    }
    __syncthreads();
    unsigned* gh = hist + img * NBUCKET;
    for (int i = threadIdx.x; i < NBUCKET; i += blockDim.x)
        if (lh[i]) atomicAdd(&gh[i], lh[i]);
}

// K2: find coarse threshold bucket B per image; also count strictly above B
__global__ void __launch_bounds__(256) k_thresh(const unsigned* __restrict__ hist,
                                                unsigned* __restrict__ bsel,
                                                unsigned* __restrict__ cntAbove) {
    __shared__ unsigned part[256];
    int img = blockIdx.x;
    int t = threadIdx.x;
    const unsigned* gh = hist + img * NBUCKET;
    unsigned s = 0;
    for (int k = 0; k < 8; ++k) s += gh[t * 8 + k];
    part[t] = s;
    __syncthreads();
    if (t == 0) {
        unsigned cum = 0;
        int done = 0;
        for (int c = 255; c >= 0 && !done; --c) {
            if (cum + part[c] >= PRE) {
                for (int i = c * 8 + 7; i >= c * 8; --i) {
                    unsigned h = gh[i];
                    if (cum + h >= PRE) { bsel[img] = (unsigned)i; cntAbove[img] = cum; done = 1; break; }
                    cum += h;
                }
            } else {
                cum += part[c];
            }
        }
    }
}

// K3: histogram of next 11 bits within coarse bucket B
__global__ void k_hist2(const float* __restrict__ obj, const unsigned* __restrict__ bsel,
                        unsigned* __restrict__ hist2) {
    __shared__ unsigned lh[NBUCKET];
    int img = blockIdx.y;
    unsigned B = bsel[img];
    for (int i = threadIdx.x; i < NBUCKET; i += blockDim.x) lh[i] = 0;
    __syncthreads();
    const float* p = obj + (size_t)img * AHW;
    int stride = gridDim.x * blockDim.x;
    for (int i = blockIdx.x * blockDim.x + threadIdx.x; i < AHW; i += stride) {
        unsigned m = mapf(p[i]);
        if ((m >> 21) == B) atomicAdd(&lh[(m >> 10) & 0x7FF], 1u);
    }
    __syncthreads();
    unsigned* gh = hist2 + img * NBUCKET;
    for (int i = threadIdx.x; i < NBUCKET; i += blockDim.x)
        if (lh[i]) atomicAdd(&gh[i], lh[i]);
}

// K4: refine to 22-bit threshold
__global__ void __launch_bounds__(256) k_thresh2(const unsigned* __restrict__ hist2,
                                                 const unsigned* __restrict__ bsel,
                                                 const unsigned* __restrict__ cntAbove,
                                                 unsigned* __restrict__ thr32) {
    __shared__ unsigned part[256];
    int img = blockIdx.x;
    int t = threadIdx.x;
    const unsigned* gh = hist2 + img * NBUCKET;
    unsigned s = 0;
    for (int k = 0; k < 8; ++k) s += gh[t * 8 + k];
    part[t] = s;
    __syncthreads();
    if (t == 0) {
        unsigned cum = cntAbove[img];
        unsigned B = bsel[img];
        int done = 0;
        for (int c = 255; c >= 0 && !done; --c) {
            if (cum + part[c] >= PRE) {
                for (int i = c * 8 + 7; i >= c * 8; --i) {
                    unsigned h = gh[i];
                    if (cum + h >= PRE) { thr32[img] = (B << 21) | ((unsigned)i << 10); done = 1; break; }
                    cum += h;
                }
            } else {
                cum += part[c];
            }
        }
    }
}

// K5: compact candidates with m >= thr into keys array
__global__ void k_compact(const float* __restrict__ obj, const unsigned* __restrict__ thr32,
                          unsigned* __restrict__ selcnt, unsigned long long* __restrict__ keys) {
    int img = blockIdx.y;
    unsigned thr = thr32[img];
    const float* p = obj + (size_t)img * AHW;
    int stride = gridDim.x * blockDim.x;
    for (int j = blockIdx.x * blockDim.x + threadIdx.x; j < AHW; j += stride) {
        unsigned m = mapf(p[j]);
        if (m >= thr) {
            int a = j >> 16;          // j = a*HW + hw  (objectness layout N,A,H,W)
            int hw = j & 65535;
            unsigned idx = (unsigned)(hw * A + a);  // candidate index in (h,w,a) order
            unsigned pos = atomicAdd(&selcnt[img], 1u);
            if (pos < CAP2)
                keys[(size_t)img * CAP2 + pos] =
                    ((unsigned long long)m << 32) | (unsigned)(~idx);
        }
    }
}

// K6: per-image bitonic sort of CAP2 keys, descending
__global__ void __launch_bounds__(1024) k_sort(unsigned long long* __restrict__ keys) {
    __shared__ unsigned long long s[CAP2];
    int img = blockIdx.x;
    unsigned long long* g = keys + (size_t)img * CAP2;
    for (int i = threadIdx.x; i < CAP2; i += 1024) s[i] = g[i];
    __syncthreads();
    for (int k2 = 2; k2 <= CAP2; k2 <<= 1) {
        for (int j = k2 >> 1; j > 0; j >>= 1) {
            for (int i = threadIdx.x; i < CAP2; i += 1024) {
                int ixj = i ^ j;
                if (ixj > i) {
                    unsigned long long a = s[i], b = s[ixj];
                    bool up = ((i & k2) == 0);
                    if (up ? (a < b) : (a > b)) { s[i] = b; s[ixj] = a; }
                }
            }
            __syncthreads();
        }
    }
    for (int i = threadIdx.x; i < PRE; i += 1024) g[i] = s[i];
}

// K7: decode boxes (f64), clip, MIN_SIZE filter, sigmoid score
__global__ void k_decode(const float* __restrict__ anchors, const float* __restrict__ br,
                         const unsigned long long* __restrict__ keys,
                         double* __restrict__ boxes, float* __restrict__ scores,
                         unsigned* __restrict__ negmask) {
    int g = blockIdx.x * blockDim.x + threadIdx.x;
    if (g >= NIMG * PRE) return;
    int img = g / PRE, r = g % PRE;
    unsigned long long key = keys[(size_t)img * CAP2 + r];
    unsigned m = (unsigned)(key >> 32);
    unsigned idx = ~(unsigned)key;
    unsigned u = (m & 0x80000000u) ? (m ^ 0x80000000u) : ~m;
    float x = __uint_as_float(u);
    double sc = 1.0 / (1.0 + exp(-(double)x));
    int a = idx % 3;
    int hw = idx / 3;
    const float* anc = anchors + ((size_t)img * AHW + idx) * 4;
    double ax1 = anc[0], ay1 = anc[1], ax2 = anc[2], ay2 = anc[3];
    double aw = ax2 - ax1 + 1.0, ah = ay2 - ay1 + 1.0;
    double cx = ax1 + 0.5 * aw, cy = ay1 + 0.5 * ah;
    const float* bp = br + (size_t)img * 12 * HW + (size_t)a * 4 * HW + hw;
    double dx = bp[0];
    double dy = bp[(size_t)HW];
    double dw = bp[(size_t)2 * HW];
    double dh = bp[(size_t)3 * HW];
    const double CLIPV = 4.135166556742356; // log(1000/16)
    dw = fmin(dw, CLIPV); dh = fmin(dh, CLIPV);
    double pcx = dx * aw + cx, pcy = dy * ah + cy;
    double pw = exp(dw) * aw, ph = exp(dh) * ah;
    double x1 = pcx - 0.5 * pw, y1 = pcy - 0.5 * ph;
    double x2 = pcx + 0.5 * pw - 1.0, y2 = pcy + 0.5 * ph - 1.0;
    x1 = fmin(fmax(x1, 0.0), 1023.0);
    y1 = fmin(fmax(y1, 0.0), 1023.0);
    x2 = fmin(fmax(x2, 0.0), 1023.0);
    y2 = fmin(fmax(y2, 0.0), 1023.0);
    bool keep = (x2 - x1 + 1.0 >= 0.0) && (y2 - y1 + 1.0 >= 0.0);
    double* bo = boxes + ((size_t)img * PRE + r) * 4;
    bo[0] = x1; bo[1] = y1; bo[2] = x2; bo[3] = y2;
    scores[img * PRE + r] = keep ? (float)sc : NEGF;
    if (!keep) atomicOr(&negmask[img * 64 + (r >> 5)], 1u << (r & 31));
}

// K8: IoU suppression bitmask, 8 rows/block, boxes staged in LDS (SoA),
// bits assembled via ballot. mask[img][r][w] bit b <-> column w*32+b.
__global__ void __launch_bounds__(64) k_mask(const double* __restrict__ boxes,
                                             unsigned* __restrict__ mask) {
    __shared__ double sx1[PRE], sy1[PRE], sx2[PRE], sy2[PRE];
    int img = blockIdx.y;
    int r0 = blockIdx.x * TILE_R;
    int t = threadIdx.x; // 0..63
    const double* base = boxes + (size_t)img * PRE * 4;
    for (int i = t; i < PRE; i += 64) {
        const double* bp = base + (size_t)i * 4;
        sx1[i] = bp[0]; sy1[i] = bp[1]; sx2[i] = bp[2]; sy2[i] = bp[3];
    }
    __syncthreads();
    for (int rr = 0; rr < TILE_R; ++rr) {
        int r = r0 + rr;
        double x1 = sx1[r], y1 = sy1[r], x2 = sx2[r], y2 = sy2[r];
        double area_r = (x2 - x1 + 1.0) * (y2 - y1 + 1.0);
        unsigned myw = 0;
        for (int k = 0; k < 32; ++k) {
            int colr = 64 * k + t;
            int col = colr < PRE ? colr : PRE - 1;
            bool cv = colr < PRE;
            double bx1 = sx1[col], by1 = sy1[col], bx2 = sx2[col], by2 = sy2[col];
            double iw = fmin(x2, bx2) - fmax(x1, bx1) + 1.0;
            double ih = fmin(y2, by2) - fmax(y1, by1) + 1.0;
            bool res = false;
            if (cv && iw > 0.0 && ih > 0.0) {
                double inter = iw * ih;
                double areaj = (bx2 - bx1 + 1.0) * (by2 - by1 + 1.0);
                double iou = inter / (area_r + areaj - inter);
                res = iou > 0.7;
            }
            unsigned long long bb = __ballot(res);
            if (t == 2 * k) myw = (unsigned)bb;
            if (t == 2 * k + 1) myw = (unsigned)(bb >> 32);
        }
        mask[((size_t)img * PRE + r) * 64 + t] = myw;
    }
}

// K9: greedy serial NMS via register bitmask + ballot pick + 1-deep speculation
__global__ void __launch_bounds__(64) k_nms(const double* __restrict__ boxes,
                                            const float* __restrict__ scores,
                                            const unsigned* __restrict__ negmask,
                                            const unsigned* __restrict__ mask,
                                            float* __restrict__ out) {
    __shared__ int picks[POST];
    __shared__ int npick;
    int img = blockIdx.x;
    int t = threadIdx.x;
    unsigned sup = negmask[img * 64 + t];
    if (t == 62) sup |= 0xFFFF0000u;  // indices 2000..2015 invalid
    if (t == 63) sup = 0xFFFFFFFFu;   // indices 2016..2047 invalid
    const unsigned* mbase = mask + (size_t)img * PRE * 64;
    int specq = -1;
    unsigned specrow = 0;
    int o = 0;
    for (; o < POST; ++o) {
        unsigned v = ~sup;
        unsigned long long b = __ballot(v != 0);
        if (b == 0) break;
        int w = __ffsll((unsigned long long)b) - 1;  // uniform
        unsigned vw = __shfl(v, w);
        int pb = __ffs(vw) - 1;
        int p = (w << 5) + pb;
        if (t == 0) picks[o] = p;
        unsigned rowp;
        if (p == specq) {
            rowp = specrow;          // speculation hit: row already in flight
        } else {
            rowp = mbase[(size_t)p * 64 + t];
        }
        // speculative next candidate: first clear bit strictly after p (pre-mask)
        unsigned vq = (t == w) ? (v & (0xFFFFFFFEu << pb)) : v;
        unsigned long long b2 = __ballot(vq != 0);
        int q = -1;
        if (b2 != 0) {
            int w2 = __ffsll((unsigned long long)b2) - 1;
            unsigned vw2 = __shfl(vq, w2);
            q = (w2 << 5) + __ffs(vw2) - 1;
        }
        unsigned nextspec = 0;
        if (q >= 0) nextspec = mbase[(size_t)q * 64 + t];  // issue early
        sup |= rowp;
        specq = q;
        specrow = nextspec;
    }
    if (t == 0) npick = o;
    __syncthreads();
    int np = npick;
    float* ob = out + (size_t)img * POST * 4;
    float* os = out + (size_t)NIMG * POST * 4 + (size_t)img * POST;
    for (int k = t; k < POST; k += 64) {
        if (k < np) {
            int p = picks[k];
            const double* bp = boxes + ((size_t)img * PRE + p) * 4;
            ob[k * 4 + 0] = (float)bp[0];
            ob[k * 4 + 1] = (float)bp[1];
            ob[k * 4 + 2] = (float)bp[2];
            ob[k * 4 + 3] = (float)bp[3];
            os[k] = scores[img * PRE + p];
        } else {
            ob[k * 4 + 0] = 0.0f; ob[k * 4 + 1] = 0.0f;
            ob[k * 4 + 2] = 0.0f; ob[k * 4 + 3] = 0.0f;
            os[k] = NEGF;
        }
    }
}

extern "C" void kernel_launch(void* const* d_in, const int* in_sizes, int n_in,
                              void* d_out, int out_size, void* d_ws, size_t ws_size,
                              hipStream_t stream) {
    const float* anchors = (const float*)d_in[0];
    const float* obj = (const float*)d_in[1];
    const float* br = (const float*)d_in[2];
    float* out = (float*)d_out;

    char* ws = (char*)d_ws;
    size_t off = 0;
    auto alloc = [&](size_t bytes) {
        void* p = ws + off;
        off = (off + bytes + 255) & ~(size_t)255;
        return p;
    };
    unsigned* hist = (unsigned*)alloc((size_t)NIMG * NBUCKET * 4);
    unsigned* hist2 = (unsigned*)alloc((size_t)NIMG * NBUCKET * 4);
    unsigned* bsel = (unsigned*)alloc(NIMG * 4);
    unsigned* cntAbove = (unsigned*)alloc(NIMG * 4);
    unsigned* thr32 = (unsigned*)alloc(NIMG * 4);
    unsigned* selcnt = (unsigned*)alloc(NIMG * 4);
    unsigned long long* keys = (unsigned long long*)alloc((size_t)NIMG * CAP2 * 8);
    double* boxes = (double*)alloc((size_t)NIMG * PRE * 4 * 8);
    float* scores = (float*)alloc((size_t)NIMG * PRE * 4);
    unsigned* negmask = (unsigned*)alloc((size_t)NIMG * 64 * 4);
    unsigned* mask = (unsigned*)alloc((size_t)NIMG * PRE * 64 * 4);

    hipMemsetAsync(hist, 0, (size_t)NIMG * NBUCKET * 4, stream);
    hipMemsetAsync(hist2, 0, (size_t)NIMG * NBUCKET * 4, stream);
    hipMemsetAsync(selcnt, 0, (size_t)NIMG * 4, stream);
    hipMemsetAsync(keys, 0, (size_t)NIMG * CAP2 * 8, stream);
    hipMemsetAsync(negmask, 0, (size_t)NIMG * 64 * 4, stream);

    k_hist<<<dim3(64, NIMG), 256, 0, stream>>>(obj, hist);
    k_thresh<<<NIMG, 256, 0, stream>>>(hist, bsel, cntAbove);
    k_hist2<<<dim3(64, NIMG), 256, 0, stream>>>(obj, bsel, hist2);
    k_thresh2<<<NIMG, 256, 0, stream>>>(hist2, bsel, cntAbove, thr32);
    k_compact<<<dim3(64, NIMG), 256, 0, stream>>>(obj, thr32, selcnt, keys);
    k_sort<<<NIMG, 1024, 0, stream>>>(keys);
    k_decode<<<(NIMG * PRE + 255) / 256, 256, 0, stream>>>(anchors, br, keys, boxes, scores, negmask);
    k_mask<<<dim3((PRE + TILE_R - 1) / TILE_R, NIMG), 64, 0, stream>>>(boxes, mask);
    k_nms<<<NIMG, 64, 0, stream>>>(boxes, scores, negmask, mask, out);
}

// Round 3
// 536.295 us; speedup vs baseline: 2.7812x; 2.2645x over previous
//
#include <hip/hip_runtime.h>
#include <math.h>

#define NIMG 16
#define A 3
#define HW 65536
#define AHW 196608
#define PRE 2000
#define POST 1000
#define CAP2 2048
#define MROWS 2048
#define NBUCKET 2048
#define NEGF (-1e30f)

__device__ __forceinline__ unsigned mapf(float x) {
    unsigned u = __float_as_uint(x);
    return (u & 0x80000000u) ? ~u : (u | 0x80000000u);
}

// K1: per-image histogram of top 11 bits of monotone-mapped objectness
__global__ void k_hist(const float* __restrict__ obj, unsigned* __restrict__ hist) {
    __shared__ unsigned lh[NBUCKET];
    int img = blockIdx.y;
    for (int i = threadIdx.x; i < NBUCKET; i += blockDim.x) lh[i] = 0;
    __syncthreads();
    const float* p = obj + (size_t)img * AHW;
    int stride = gridDim.x * blockDim.x;
    for (int i = blockIdx.x * blockDim.x + threadIdx.x; i < AHW; i += stride) {
        unsigned m = mapf(p[i]);
        atomicAdd(&lh[m >> 21], 1u);
    }
    __syncthreads();
    unsigned* gh = hist + img * NBUCKET;
    for (int i = threadIdx.x; i < NBUCKET; i += blockDim.x)
        if (lh[i]) atomicAdd(&gh[i], lh[i]);
}

// K2: find coarse threshold bucket B per image; also count strictly above B
__global__ void __launch_bounds__(256) k_thresh(const unsigned* __restrict__ hist,
                                                unsigned* __restrict__ bsel,
                                                unsigned* __restrict__ cntAbove) {
    __shared__ unsigned part[256];
    int img = blockIdx.x;
    int t = threadIdx.x;
    const unsigned* gh = hist + img * NBUCKET;
    unsigned s = 0;
    for (int k = 0; k < 8; ++k) s += gh[t * 8 + k];
    part[t] = s;
    __syncthreads();
    if (t == 0) {
        unsigned cum = 0;
        int done = 0;
        for (int c = 255; c >= 0 && !done; --c) {
            if (cum + part[c] >= PRE) {
                for (int i = c * 8 + 7; i >= c * 8; --i) {
                    unsigned h = gh[i];
                    if (cum + h >= PRE) { bsel[img] = (unsigned)i; cntAbove[img] = cum; done = 1; break; }
                    cum += h;
                }
            } else {
                cum += part[c];
            }
        }
    }
}

// K3: histogram of next 11 bits within coarse bucket B
__global__ void k_hist2(const float* __restrict__ obj, const unsigned* __restrict__ bsel,
                        unsigned* __restrict__ hist2) {
    __shared__ unsigned lh[NBUCKET];
    int img = blockIdx.y;
    unsigned B = bsel[img];
    for (int i = threadIdx.x; i < NBUCKET; i += blockDim.x) lh[i] = 0;
    __syncthreads();
    const float* p = obj + (size_t)img * AHW;
    int stride = gridDim.x * blockDim.x;
    for (int i = blockIdx.x * blockDim.x + threadIdx.x; i < AHW; i += stride) {
        unsigned m = mapf(p[i]);
        if ((m >> 21) == B) atomicAdd(&lh[(m >> 10) & 0x7FF], 1u);
    }
    __syncthreads();
    unsigned* gh = hist2 + img * NBUCKET;
    for (int i = threadIdx.x; i < NBUCKET; i += blockDim.x)
        if (lh[i]) atomicAdd(&gh[i], lh[i]);
}

// K4: refine to 22-bit threshold
__global__ void __launch_bounds__(256) k_thresh2(const unsigned* __restrict__ hist2,
                                                 const unsigned* __restrict__ bsel,
                                                 const unsigned* __restrict__ cntAbove,
                                                 unsigned* __restrict__ thr32) {
    __shared__ unsigned part[256];
    int img = blockIdx.x;
    int t = threadIdx.x;
    const unsigned* gh = hist2 + img * NBUCKET;
    unsigned s = 0;
    for (int k = 0; k < 8; ++k) s += gh[t * 8 + k];
    part[t] = s;
    __syncthreads();
    if (t == 0) {
        unsigned cum = cntAbove[img];
        unsigned B = bsel[img];
        int done = 0;
        for (int c = 255; c >= 0 && !done; --c) {
            if (cum + part[c] >= PRE) {
                for (int i = c * 8 + 7; i >= c * 8; --i) {
                    unsigned h = gh[i];
                    if (cum + h >= PRE) { thr32[img] = (B << 21) | ((unsigned)i << 10); done = 1; break; }
                    cum += h;
                }
            } else {
                cum += part[c];
            }
        }
    }
}

// K5: compact candidates with m >= thr into keys array
__global__ void k_compact(const float* __restrict__ obj, const unsigned* __restrict__ thr32,
                          unsigned* __restrict__ selcnt, unsigned long long* __restrict__ keys) {
    int img = blockIdx.y;
    unsigned thr = thr32[img];
    const float* p = obj + (size_t)img * AHW;
    int stride = gridDim.x * blockDim.x;
    for (int j = blockIdx.x * blockDim.x + threadIdx.x; j < AHW; j += stride) {
        unsigned m = mapf(p[j]);
        if (m >= thr) {
            int a = j >> 16;
            int hw = j & 65535;
            unsigned idx = (unsigned)(hw * A + a);
            unsigned pos = atomicAdd(&selcnt[img], 1u);
            if (pos < CAP2)
                keys[(size_t)img * CAP2 + pos] =
                    ((unsigned long long)m << 32) | (unsigned)(~idx);
        }
    }
}

// K6: per-image bitonic sort of CAP2 keys, descending
__global__ void __launch_bounds__(1024) k_sort(unsigned long long* __restrict__ keys) {
    __shared__ unsigned long long s[CAP2];
    int img = blockIdx.x;
    unsigned long long* g = keys + (size_t)img * CAP2;
    for (int i = threadIdx.x; i < CAP2; i += 1024) s[i] = g[i];
    __syncthreads();
    for (int k2 = 2; k2 <= CAP2; k2 <<= 1) {
        for (int j = k2 >> 1; j > 0; j >>= 1) {
            for (int i = threadIdx.x; i < CAP2; i += 1024) {
                int ixj = i ^ j;
                if (ixj > i) {
                    unsigned long long a = s[i], b = s[ixj];
                    bool up = ((i & k2) == 0);
                    if (up ? (a < b) : (a > b)) { s[i] = b; s[ixj] = a; }
                }
            }
            __syncthreads();
        }
    }
    for (int i = threadIdx.x; i < PRE; i += 1024) g[i] = s[i];
}

// K7: decode boxes (f64), clip, MIN_SIZE filter, sigmoid score
__global__ void k_decode(const float* __restrict__ anchors, const float* __restrict__ br,
                         const unsigned long long* __restrict__ keys,
                         double* __restrict__ boxes, float* __restrict__ scores,
                         unsigned* __restrict__ negmask) {
    int g = blockIdx.x * blockDim.x + threadIdx.x;
    if (g >= NIMG * PRE) return;
    int img = g / PRE, r = g % PRE;
    unsigned long long key = keys[(size_t)img * CAP2 + r];
    unsigned m = (unsigned)(key >> 32);
    unsigned idx = ~(unsigned)key;
    unsigned u = (m & 0x80000000u) ? (m ^ 0x80000000u) : ~m;
    float x = __uint_as_float(u);
    double sc = 1.0 / (1.0 + exp(-(double)x));
    int a = idx % 3;
    int hw = idx / 3;
    const float* anc = anchors + ((size_t)img * AHW + idx) * 4;
    double ax1 = anc[0], ay1 = anc[1], ax2 = anc[2], ay2 = anc[3];
    double aw = ax2 - ax1 + 1.0, ah = ay2 - ay1 + 1.0;
    double cx = ax1 + 0.5 * aw, cy = ay1 + 0.5 * ah;
    const float* bp = br + (size_t)img * 12 * HW + (size_t)a * 4 * HW + hw;
    double dx = bp[0];
    double dy = bp[(size_t)HW];
    double dw = bp[(size_t)2 * HW];
    double dh = bp[(size_t)3 * HW];
    const double CLIPV = 4.135166556742356; // log(1000/16)
    dw = fmin(dw, CLIPV); dh = fmin(dh, CLIPV);
    double pcx = dx * aw + cx, pcy = dy * ah + cy;
    double pw = exp(dw) * aw, ph = exp(dh) * ah;
    double x1 = pcx - 0.5 * pw, y1 = pcy - 0.5 * ph;
    double x2 = pcx + 0.5 * pw - 1.0, y2 = pcy + 0.5 * ph - 1.0;
    x1 = fmin(fmax(x1, 0.0), 1023.0);
    y1 = fmin(fmax(y1, 0.0), 1023.0);
    x2 = fmin(fmax(x2, 0.0), 1023.0);
    y2 = fmin(fmax(y2, 0.0), 1023.0);
    bool keep = (x2 - x1 + 1.0 >= 0.0) && (y2 - y1 + 1.0 >= 0.0);
    double* bo = boxes + ((size_t)img * PRE + r) * 4;
    bo[0] = x1; bo[1] = y1; bo[2] = x2; bo[3] = y2;
    scores[img * PRE + r] = keep ? (float)sc : NEGF;
    if (!keep) atomicOr(&negmask[img * 64 + (r >> 5)], 1u << (r & 31));
}

// K8: upper-triangle IoU suppression bitmask. 4 waves x 8 rows = 32 rows/block,
// boxes staged once in LDS (SoA). Row r: only word-blocks k >= r>>6 computed,
// lower words written as 0. mask[img][r][w] bit b <-> column w*32+b.
__global__ void __launch_bounds__(256) k_mask(const double* __restrict__ boxes,
                                              unsigned* __restrict__ mask) {
    __shared__ double sx1[PRE], sy1[PRE], sx2[PRE], sy2[PRE];
    int img = blockIdx.y;
    int tid = threadIdx.x;
    int wave = tid >> 6, t = tid & 63;
    const double* base = boxes + (size_t)img * PRE * 4;
    for (int i = tid; i < PRE; i += 256) {
        const double* bp = base + (size_t)i * 4;
        sx1[i] = bp[0]; sy1[i] = bp[1]; sx2[i] = bp[2]; sy2[i] = bp[3];
    }
    __syncthreads();
    int rb = blockIdx.x * 32 + wave * 8;
    for (int rr = 0; rr < 8; ++rr) {
        int r = rb + rr;
        if (r >= PRE) break;
        double x1 = sx1[r], y1 = sy1[r], x2 = sx2[r], y2 = sy2[r];
        double area_r = (x2 - x1 + 1.0) * (y2 - y1 + 1.0);
        int kmin = r >> 6;
        unsigned myw = 0;
        for (int k = kmin; k < 32; ++k) {
            int colr = 64 * k + t;
            int col = colr < PRE ? colr : PRE - 1;
            bool cv = colr < PRE;
            double bx1 = sx1[col], by1 = sy1[col], bx2 = sx2[col], by2 = sy2[col];
            double iw = fmin(x2, bx2) - fmax(x1, bx1) + 1.0;
            double ih = fmin(y2, by2) - fmax(y1, by1) + 1.0;
            bool res = false;
            if (cv && iw > 0.0 && ih > 0.0) {
                double inter = iw * ih;
                double areaj = (bx2 - bx1 + 1.0) * (by2 - by1 + 1.0);
                double iou = inter / (area_r + areaj - inter);
                res = iou > 0.7;
            }
            unsigned long long bb = __ballot(res);
            if (t == 2 * k) myw = (unsigned)bb;
            if (t == 2 * k + 1) myw = (unsigned)(bb >> 32);
        }
        mask[((size_t)img * MROWS + r) * 64 + t] = myw;
    }
}

// K9: sequential-scan greedy NMS. Scores sorted desc => greedy pick == first
// unsuppressed index. Row addresses known ahead => 16-deep static prefetch
// ring; serial chain is just readlane + bit test + conditional OR.
__global__ void __launch_bounds__(64) k_nms(const double* __restrict__ boxes,
                                            const float* __restrict__ scores,
                                            const unsigned* __restrict__ negmask,
                                            const unsigned* __restrict__ mask,
                                            float* __restrict__ out) {
    __shared__ int picks[POST];
    int img = blockIdx.x;
    int t = threadIdx.x;
    unsigned sup = negmask[img * 64 + t];
    if (t == 62) sup |= 0xFFFF0000u;  // indices 2000..2015 invalid
    if (t == 63) sup = 0xFFFFFFFFu;   // indices 2016..2047 invalid
    const unsigned* mbase = mask + (size_t)img * MROWS * 64;
    unsigned rbuf[16];
    #pragma unroll
    for (int s = 0; s < 16; ++s) rbuf[s] = mbase[(size_t)s * 64 + t];
    int np = 0;
    for (int g = 0; g < PRE / 16; ++g) {
        #pragma unroll
        for (int s = 0; s < 16; ++s) {
            int jj = g * 16 + s;
            unsigned w = (unsigned)__builtin_amdgcn_readlane((int)sup, jj >> 5);
            bool alive = ((w >> (jj & 31)) & 1u) == 0u;
            unsigned r = rbuf[s];
            rbuf[s] = mbase[(size_t)(jj + 16) * 64 + t];  // prefetch 16 ahead (rows padded to MROWS)
            if (alive && np < POST) {
                sup |= r;
                if (t == 0) picks[np] = jj;
                np++;
            }
        }
        if (np >= POST) break;
    }
    __syncthreads();
    float* ob = out + (size_t)img * POST * 4;
    float* os = out + (size_t)NIMG * POST * 4 + (size_t)img * POST;
    for (int k = t; k < POST; k += 64) {
        if (k < np) {
            int p = picks[k];
            const double* bp = boxes + ((size_t)img * PRE + p) * 4;
            ob[k * 4 + 0] = (float)bp[0];
            ob[k * 4 + 1] = (float)bp[1];
            ob[k * 4 + 2] = (float)bp[2];
            ob[k * 4 + 3] = (float)bp[3];
            os[k] = scores[img * PRE + p];
        } else {
            ob[k * 4 + 0] = 0.0f; ob[k * 4 + 1] = 0.0f;
            ob[k * 4 + 2] = 0.0f; ob[k * 4 + 3] = 0.0f;
            os[k] = NEGF;
        }
    }
}

extern "C" void kernel_launch(void* const* d_in, const int* in_sizes, int n_in,
                              void* d_out, int out_size, void* d_ws, size_t ws_size,
                              hipStream_t stream) {
    const float* anchors = (const float*)d_in[0];
    const float* obj = (const float*)d_in[1];
    const float* br = (const float*)d_in[2];
    float* out = (float*)d_out;

    char* ws = (char*)d_ws;
    size_t off = 0;
    auto alloc = [&](size_t bytes) {
        void* p = ws + off;
        off = (off + bytes + 255) & ~(size_t)255;
        return p;
    };
    unsigned* hist = (unsigned*)alloc((size_t)NIMG * NBUCKET * 4);   // contiguous with hist2
    unsigned* hist2 = (unsigned*)alloc((size_t)NIMG * NBUCKET * 4);
    unsigned* bsel = (unsigned*)alloc(NIMG * 4);
    unsigned* cntAbove = (unsigned*)alloc(NIMG * 4);
    unsigned* thr32 = (unsigned*)alloc(NIMG * 4);
    unsigned* selcnt = (unsigned*)alloc(NIMG * 4);
    unsigned long long* keys = (unsigned long long*)alloc((size_t)NIMG * CAP2 * 8);
    double* boxes = (double*)alloc((size_t)NIMG * PRE * 4 * 8);
    float* scores = (float*)alloc((size_t)NIMG * PRE * 4);
    unsigned* negmask = (unsigned*)alloc((size_t)NIMG * 64 * 4);
    unsigned* mask = (unsigned*)alloc((size_t)NIMG * MROWS * 64 * 4);

    hipMemsetAsync(hist, 0, (size_t)NIMG * NBUCKET * 4 * 2, stream); // hist + hist2
    hipMemsetAsync(selcnt, 0, (size_t)NIMG * 4, stream);
    hipMemsetAsync(keys, 0, (size_t)NIMG * CAP2 * 8, stream);
    hipMemsetAsync(negmask, 0, (size_t)NIMG * 64 * 4, stream);

    k_hist<<<dim3(64, NIMG), 256, 0, stream>>>(obj, hist);
    k_thresh<<<NIMG, 256, 0, stream>>>(hist, bsel, cntAbove);
    k_hist2<<<dim3(64, NIMG), 256, 0, stream>>>(obj, bsel, hist2);
    k_thresh2<<<NIMG, 256, 0, stream>>>(hist2, bsel, cntAbove, thr32);
    k_compact<<<dim3(64, NIMG), 256, 0, stream>>>(obj, thr32, selcnt, keys);
    k_sort<<<NIMG, 1024, 0, stream>>>(keys);
    k_decode<<<(NIMG * PRE + 255) / 256, 256, 0, stream>>>(anchors, br, keys, boxes, scores, negmask);
    k_mask<<<dim3((PRE + 31) / 32, NIMG), 256, 0, stream>>>(boxes, mask);
    k_nms<<<NIMG, 64, 0, stream>>>(boxes, scores, negmask, mask, out);
}

// Round 4
// 267.274 us; speedup vs baseline: 5.5806x; 2.0065x over previous
//
#include <hip/hip_runtime.h>
#include <math.h>

#define NIMG 16
#define A 3
#define HW 65536
#define AHW 196608
#define PRE 2000
#define POST 1000
#define CAP2 2048
#define MROWS 2048
#define NBUCKET 2048
#define NEGF (-1e30f)
#define LBUF 256

__device__ __forceinline__ unsigned mapf(float x) {
    unsigned u = __float_as_uint(x);
    return (u & 0x80000000u) ? ~u : (u | 0x80000000u);
}

// K1: per-image histogram of top 11 bits of monotone-mapped objectness (float4 loads)
__global__ void __launch_bounds__(256) k_hist(const float4* __restrict__ obj4,
                                              unsigned* __restrict__ hist) {
    __shared__ unsigned lh[NBUCKET];
    int img = blockIdx.y;
    for (int i = threadIdx.x; i < NBUCKET; i += 256) lh[i] = 0;
    __syncthreads();
    const float4* p = obj4 + (size_t)img * (AHW / 4);
    int stride = gridDim.x * 256;
    for (int v = blockIdx.x * 256 + threadIdx.x; v < AHW / 4; v += stride) {
        float4 f = p[v];
        atomicAdd(&lh[mapf(f.x) >> 21], 1u);
        atomicAdd(&lh[mapf(f.y) >> 21], 1u);
        atomicAdd(&lh[mapf(f.z) >> 21], 1u);
        atomicAdd(&lh[mapf(f.w) >> 21], 1u);
    }
    __syncthreads();
    unsigned* gh = hist + img * NBUCKET;
    for (int i = threadIdx.x; i < NBUCKET; i += 256)
        if (lh[i]) atomicAdd(&gh[i], lh[i]);
}

// K2: find coarse threshold bucket B per image; also count strictly above B
__global__ void __launch_bounds__(256) k_thresh(const unsigned* __restrict__ hist,
                                                unsigned* __restrict__ bsel,
                                                unsigned* __restrict__ cntAbove) {
    __shared__ unsigned part[256];
    int img = blockIdx.x;
    int t = threadIdx.x;
    const unsigned* gh = hist + img * NBUCKET;
    unsigned s = 0;
    for (int k = 0; k < 8; ++k) s += gh[t * 8 + k];
    part[t] = s;
    __syncthreads();
    if (t == 0) {
        unsigned cum = 0;
        int done = 0;
        for (int c = 255; c >= 0 && !done; --c) {
            if (cum + part[c] >= PRE) {
                for (int i = c * 8 + 7; i >= c * 8; --i) {
                    unsigned h = gh[i];
                    if (cum + h >= PRE) { bsel[img] = (unsigned)i; cntAbove[img] = cum; done = 1; break; }
                    cum += h;
                }
            } else {
                cum += part[c];
            }
        }
    }
}

// K3: histogram of next 11 bits within coarse bucket B (float4 loads)
__global__ void __launch_bounds__(256) k_hist2(const float4* __restrict__ obj4,
                                               const unsigned* __restrict__ bsel,
                                               unsigned* __restrict__ hist2) {
    __shared__ unsigned lh[NBUCKET];
    int img = blockIdx.y;
    unsigned B = bsel[img];
    for (int i = threadIdx.x; i < NBUCKET; i += 256) lh[i] = 0;
    __syncthreads();
    const float4* p = obj4 + (size_t)img * (AHW / 4);
    int stride = gridDim.x * 256;
    for (int v = blockIdx.x * 256 + threadIdx.x; v < AHW / 4; v += stride) {
        float4 f = p[v];
        unsigned m0 = mapf(f.x), m1 = mapf(f.y), m2 = mapf(f.z), m3 = mapf(f.w);
        if ((m0 >> 21) == B) atomicAdd(&lh[(m0 >> 10) & 0x7FF], 1u);
        if ((m1 >> 21) == B) atomicAdd(&lh[(m1 >> 10) & 0x7FF], 1u);
        if ((m2 >> 21) == B) atomicAdd(&lh[(m2 >> 10) & 0x7FF], 1u);
        if ((m3 >> 21) == B) atomicAdd(&lh[(m3 >> 10) & 0x7FF], 1u);
    }
    __syncthreads();
    unsigned* gh = hist2 + img * NBUCKET;
    for (int i = threadIdx.x; i < 256; i += 256) {}
    for (int i = threadIdx.x; i < NBUCKET; i += 256)
        if (lh[i]) atomicAdd(&gh[i], lh[i]);
}

// K4: refine to 22-bit threshold
__global__ void __launch_bounds__(256) k_thresh2(const unsigned* __restrict__ hist2,
                                                 const unsigned* __restrict__ bsel,
                                                 const unsigned* __restrict__ cntAbove,
                                                 unsigned* __restrict__ thr32) {
    __shared__ unsigned part[256];
    int img = blockIdx.x;
    int t = threadIdx.x;
    const unsigned* gh = hist2 + img * NBUCKET;
    unsigned s = 0;
    for (int k = 0; k < 8; ++k) s += gh[t * 8 + k];
    part[t] = s;
    __syncthreads();
    if (t == 0) {
        unsigned cum = cntAbove[img];
        unsigned B = bsel[img];
        int done = 0;
        for (int c = 255; c >= 0 && !done; --c) {
            if (cum + part[c] >= PRE) {
                for (int i = c * 8 + 7; i >= c * 8; --i) {
                    unsigned h = gh[i];
                    if (cum + h >= PRE) { thr32[img] = (B << 21) | ((unsigned)i << 10); done = 1; break; }
                    cum += h;
                }
            } else {
                cum += part[c];
            }
        }
    }
}

// K5: compact candidates with m >= thr. Two-level: LDS staging + one global
// atomic per block (selcnt padded to a private cache line per image).
__global__ void __launch_bounds__(256) k_compact(const float4* __restrict__ obj4,
                                                 const unsigned* __restrict__ thr32,
                                                 unsigned* __restrict__ selcnt,
                                                 unsigned long long* __restrict__ keys) {
    __shared__ unsigned long long lbuf[LBUF];
    __shared__ unsigned lcnt, gbase;
    int img = blockIdx.y;
    unsigned thr = thr32[img];
    if (threadIdx.x == 0) lcnt = 0;
    __syncthreads();
    const float4* p = obj4 + (size_t)img * (AHW / 4);
    // block handles contiguous chunk of 3072 floats = 768 float4
    int v0 = blockIdx.x * 768;
    #pragma unroll
    for (int it = 0; it < 3; ++it) {
        int v = v0 + it * 256 + threadIdx.x;
        float4 f = p[v];
        int jb = v * 4;
        #pragma unroll
        for (int k = 0; k < 4; ++k) {
            float x = k == 0 ? f.x : (k == 1 ? f.y : (k == 2 ? f.z : f.w));
            unsigned m = mapf(x);
            if (m >= thr) {
                int j = jb + k;
                int a = j >> 16;
                int hw = j & 65535;
                unsigned idx = (unsigned)(hw * A + a);
                unsigned pos = atomicAdd(&lcnt, 1u);
                if (pos < LBUF)
                    lbuf[pos] = ((unsigned long long)m << 32) | (unsigned)(~idx);
            }
        }
    }
    __syncthreads();
    unsigned n = lcnt > LBUF ? LBUF : lcnt;
    if (threadIdx.x == 0) gbase = atomicAdd(&selcnt[img * 64], n);
    __syncthreads();
    if (threadIdx.x < n) {
        unsigned pos = gbase + threadIdx.x;
        if (pos < CAP2)
            keys[(size_t)img * CAP2 + pos] = lbuf[threadIdx.x];
    }
}

// K6: per-image bitonic sort of CAP2 keys, descending
__global__ void __launch_bounds__(1024) k_sort(unsigned long long* __restrict__ keys) {
    __shared__ unsigned long long s[CAP2];
    int img = blockIdx.x;
    unsigned long long* g = keys + (size_t)img * CAP2;
    for (int i = threadIdx.x; i < CAP2; i += 1024) s[i] = g[i];
    __syncthreads();
    for (int k2 = 2; k2 <= CAP2; k2 <<= 1) {
        for (int j = k2 >> 1; j > 0; j >>= 1) {
            for (int i = threadIdx.x; i < CAP2; i += 1024) {
                int ixj = i ^ j;
                if (ixj > i) {
                    unsigned long long a = s[i], b = s[ixj];
                    bool up = ((i & k2) == 0);
                    if (up ? (a < b) : (a > b)) { s[i] = b; s[ixj] = a; }
                }
            }
            __syncthreads();
        }
    }
    for (int i = threadIdx.x; i < PRE; i += 1024) g[i] = s[i];
}

// K7: decode boxes (f64), clip, MIN_SIZE filter, sigmoid score
__global__ void k_decode(const float* __restrict__ anchors, const float* __restrict__ br,
                         const unsigned long long* __restrict__ keys,
                         double* __restrict__ boxes, float* __restrict__ scores,
                         unsigned* __restrict__ negmask) {
    int g = blockIdx.x * blockDim.x + threadIdx.x;
    if (g >= NIMG * PRE) return;
    int img = g / PRE, r = g % PRE;
    unsigned long long key = keys[(size_t)img * CAP2 + r];
    unsigned m = (unsigned)(key >> 32);
    unsigned idx = ~(unsigned)key;
    unsigned u = (m & 0x80000000u) ? (m ^ 0x80000000u) : ~m;
    float x = __uint_as_float(u);
    double sc = 1.0 / (1.0 + exp(-(double)x));
    int a = idx % 3;
    int hw = idx / 3;
    const float* anc = anchors + ((size_t)img * AHW + idx) * 4;
    double ax1 = anc[0], ay1 = anc[1], ax2 = anc[2], ay2 = anc[3];
    double aw = ax2 - ax1 + 1.0, ah = ay2 - ay1 + 1.0;
    double cx = ax1 + 0.5 * aw, cy = ay1 + 0.5 * ah;
    const float* bp = br + (size_t)img * 12 * HW + (size_t)a * 4 * HW + hw;
    double dx = bp[0];
    double dy = bp[(size_t)HW];
    double dw = bp[(size_t)2 * HW];
    double dh = bp[(size_t)3 * HW];
    const double CLIPV = 4.135166556742356; // log(1000/16)
    dw = fmin(dw, CLIPV); dh = fmin(dh, CLIPV);
    double pcx = dx * aw + cx, pcy = dy * ah + cy;
    double pw = exp(dw) * aw, ph = exp(dh) * ah;
    double x1 = pcx - 0.5 * pw, y1 = pcy - 0.5 * ph;
    double x2 = pcx + 0.5 * pw - 1.0, y2 = pcy + 0.5 * ph - 1.0;
    x1 = fmin(fmax(x1, 0.0), 1023.0);
    y1 = fmin(fmax(y1, 0.0), 1023.0);
    x2 = fmin(fmax(x2, 0.0), 1023.0);
    y2 = fmin(fmax(y2, 0.0), 1023.0);
    bool keep = (x2 - x1 + 1.0 >= 0.0) && (y2 - y1 + 1.0 >= 0.0);
    double* bo = boxes + ((size_t)img * PRE + r) * 4;
    bo[0] = x1; bo[1] = y1; bo[2] = x2; bo[3] = y2;
    scores[img * PRE + r] = keep ? (float)sc : NEGF;
    if (!keep) atomicOr(&negmask[img * 64 + (r >> 5)], 1u << (r & 31));
}

// K8: upper-triangle IoU suppression bitmask. 4 waves x 8 rows = 32 rows/block,
// boxes staged once in LDS (SoA). Row r: only word-blocks k >= r>>6 computed.
__global__ void __launch_bounds__(256) k_mask(const double* __restrict__ boxes,
                                              unsigned* __restrict__ mask) {
    __shared__ double sx1[PRE], sy1[PRE], sx2[PRE], sy2[PRE];
    int img = blockIdx.y;
    int tid = threadIdx.x;
    int wave = tid >> 6, t = tid & 63;
    const double* base = boxes + (size_t)img * PRE * 4;
    for (int i = tid; i < PRE; i += 256) {
        const double* bp = base + (size_t)i * 4;
        sx1[i] = bp[0]; sy1[i] = bp[1]; sx2[i] = bp[2]; sy2[i] = bp[3];
    }
    __syncthreads();
    int rb = blockIdx.x * 32 + wave * 8;
    for (int rr = 0; rr < 8; ++rr) {
        int r = rb + rr;
        if (r >= PRE) break;
        double x1 = sx1[r], y1 = sy1[r], x2 = sx2[r], y2 = sy2[r];
        double area_r = (x2 - x1 + 1.0) * (y2 - y1 + 1.0);
        int kmin = r >> 6;
        unsigned myw = 0;
        for (int k = kmin; k < 32; ++k) {
            int colr = 64 * k + t;
            int col = colr < PRE ? colr : PRE - 1;
            bool cv = colr < PRE;
            double bx1 = sx1[col], by1 = sy1[col], bx2 = sx2[col], by2 = sy2[col];
            double iw = fmin(x2, bx2) - fmax(x1, bx1) + 1.0;
            double ih = fmin(y2, by2) - fmax(y1, by1) + 1.0;
            bool res = false;
            if (cv && iw > 0.0 && ih > 0.0) {
                double inter = iw * ih;
                double areaj = (bx2 - bx1 + 1.0) * (by2 - by1 + 1.0);
                double iou = inter / (area_r + areaj - inter);
                res = iou > 0.7;
            }
            unsigned long long bb = __ballot(res);
            if (t == 2 * k) myw = (unsigned)bb;
            if (t == 2 * k + 1) myw = (unsigned)(bb >> 32);
        }
        mask[((size_t)img * MROWS + r) * 64 + t] = myw;
    }
}

// K9: sequential-scan greedy NMS with 16-deep static prefetch ring.
__global__ void __launch_bounds__(64) k_nms(const double* __restrict__ boxes,
                                            const float* __restrict__ scores,
                                            const unsigned* __restrict__ negmask,
                                            const unsigned* __restrict__ mask,
                                            float* __restrict__ out) {
    __shared__ int picks[POST];
    int img = blockIdx.x;
    int t = threadIdx.x;
    unsigned sup = negmask[img * 64 + t];
    if (t == 62) sup |= 0xFFFF0000u;  // indices 2000..2015 invalid
    if (t == 63) sup = 0xFFFFFFFFu;   // indices 2016..2047 invalid
    const unsigned* mbase = mask + (size_t)img * MROWS * 64;
    unsigned rbuf[16];
    #pragma unroll
    for (int s = 0; s < 16; ++s) rbuf[s] = mbase[(size_t)s * 64 + t];
    int np = 0;
    for (int g = 0; g < PRE / 16; ++g) {
        #pragma unroll
        for (int s = 0; s < 16; ++s) {
            int jj = g * 16 + s;
            unsigned w = (unsigned)__builtin_amdgcn_readlane((int)sup, jj >> 5);
            bool alive = ((w >> (jj & 31)) & 1u) == 0u;
            unsigned r = rbuf[s];
            rbuf[s] = mbase[(size_t)(jj + 16) * 64 + t];  // rows padded to MROWS
            if (alive && np < POST) {
                sup |= r;
                if (t == 0) picks[np] = jj;
                np++;
            }
        }
        if (np >= POST) break;
    }
    __syncthreads();
    float* ob = out + (size_t)img * POST * 4;
    float* os = out + (size_t)NIMG * POST * 4 + (size_t)img * POST;
    for (int k = t; k < POST; k += 64) {
        if (k < np) {
            int p = picks[k];
            const double* bp = boxes + ((size_t)img * PRE + p) * 4;
            ob[k * 4 + 0] = (float)bp[0];
            ob[k * 4 + 1] = (float)bp[1];
            ob[k * 4 + 2] = (float)bp[2];
            ob[k * 4 + 3] = (float)bp[3];
            os[k] = scores[img * PRE + p];
        } else {
            ob[k * 4 + 0] = 0.0f; ob[k * 4 + 1] = 0.0f;
            ob[k * 4 + 2] = 0.0f; ob[k * 4 + 3] = 0.0f;
            os[k] = NEGF;
        }
    }
}

extern "C" void kernel_launch(void* const* d_in, const int* in_sizes, int n_in,
                              void* d_out, int out_size, void* d_ws, size_t ws_size,
                              hipStream_t stream) {
    const float* anchors = (const float*)d_in[0];
    const float4* obj4 = (const float4*)d_in[1];
    const float* br = (const float*)d_in[2];
    float* out = (float*)d_out;

    char* ws = (char*)d_ws;
    size_t off = 0;
    auto alloc = [&](size_t bytes) {
        void* p = ws + off;
        off = (off + bytes + 255) & ~(size_t)255;
        return p;
    };
    unsigned* hist = (unsigned*)alloc((size_t)NIMG * NBUCKET * 4);   // contiguous with hist2
    unsigned* hist2 = (unsigned*)alloc((size_t)NIMG * NBUCKET * 4);
    unsigned* bsel = (unsigned*)alloc(NIMG * 4);
    unsigned* cntAbove = (unsigned*)alloc(NIMG * 4);
    unsigned* thr32 = (unsigned*)alloc(NIMG * 4);
    unsigned* selcnt = (unsigned*)alloc((size_t)NIMG * 64 * 4);      // one cache line per image
    unsigned long long* keys = (unsigned long long*)alloc((size_t)NIMG * CAP2 * 8);
    double* boxes = (double*)alloc((size_t)NIMG * PRE * 4 * 8);
    float* scores = (float*)alloc((size_t)NIMG * PRE * 4);
    unsigned* negmask = (unsigned*)alloc((size_t)NIMG * 64 * 4);
    unsigned* mask = (unsigned*)alloc((size_t)NIMG * MROWS * 64 * 4);

    hipMemsetAsync(hist, 0, (size_t)NIMG * NBUCKET * 4 * 2, stream); // hist + hist2
    hipMemsetAsync(selcnt, 0, (size_t)NIMG * 64 * 4, stream);
    hipMemsetAsync(keys, 0, (size_t)NIMG * CAP2 * 8, stream);
    hipMemsetAsync(negmask, 0, (size_t)NIMG * 64 * 4, stream);

    k_hist<<<dim3(64, NIMG), 256, 0, stream>>>(obj4, hist);
    k_thresh<<<NIMG, 256, 0, stream>>>(hist, bsel, cntAbove);
    k_hist2<<<dim3(64, NIMG), 256, 0, stream>>>(obj4, bsel, hist2);
    k_thresh2<<<NIMG, 256, 0, stream>>>(hist2, bsel, cntAbove, thr32);
    k_compact<<<dim3(64, NIMG), 256, 0, stream>>>(obj4, thr32, selcnt, keys);
    k_sort<<<NIMG, 1024, 0, stream>>>(keys);
    k_decode<<<(NIMG * PRE + 255) / 256, 256, 0, stream>>>(anchors, br, keys, boxes, scores, negmask);
    k_mask<<<dim3((PRE + 31) / 32, NIMG), 256, 0, stream>>>(boxes, mask);
    k_nms<<<NIMG, 64, 0, stream>>>(boxes, scores, negmask, mask, out);
}

// Round 5
// 220.246 us; speedup vs baseline: 6.7722x; 1.2135x over previous
//
#include <hip/hip_runtime.h>
#include <math.h>

#define NIMG 16
#define A 3
#define HW 65536
#define AHW 196608
#define PRE 2000
#define POST 1000
#define CAP2 2048
#define MROWS 2048
#define NBUCKET 2048
#define NEGF (-1e30f)
#define LBUF 256
#define BW 0.01f
#define BD 4.0f

__device__ __forceinline__ unsigned mapf(float x) {
    unsigned u = __float_as_uint(x);
    return (u & 0x80000000u) ? ~u : (u | 0x80000000u);
}

// K1: per-image histogram of top 11 bits of monotone-mapped objectness (float4 loads)
__global__ void __launch_bounds__(256) k_hist(const float4* __restrict__ obj4,
                                              unsigned* __restrict__ hist) {
    __shared__ unsigned lh[NBUCKET];
    int img = blockIdx.y;
    for (int i = threadIdx.x; i < NBUCKET; i += 256) lh[i] = 0;
    __syncthreads();
    const float4* p = obj4 + (size_t)img * (AHW / 4);
    int stride = gridDim.x * 256;
    for (int v = blockIdx.x * 256 + threadIdx.x; v < AHW / 4; v += stride) {
        float4 f = p[v];
        atomicAdd(&lh[mapf(f.x) >> 21], 1u);
        atomicAdd(&lh[mapf(f.y) >> 21], 1u);
        atomicAdd(&lh[mapf(f.z) >> 21], 1u);
        atomicAdd(&lh[mapf(f.w) >> 21], 1u);
    }
    __syncthreads();
    unsigned* gh = hist + img * NBUCKET;
    for (int i = threadIdx.x; i < NBUCKET; i += 256)
        if (lh[i]) atomicAdd(&gh[i], lh[i]);
}

// K2: find coarse threshold bucket B per image; also count strictly above B
__global__ void __launch_bounds__(256) k_thresh(const unsigned* __restrict__ hist,
                                                unsigned* __restrict__ bsel,
                                                unsigned* __restrict__ cntAbove) {
    __shared__ unsigned part[256];
    int img = blockIdx.x;
    int t = threadIdx.x;
    const unsigned* gh = hist + img * NBUCKET;
    unsigned s = 0;
    for (int k = 0; k < 8; ++k) s += gh[t * 8 + k];
    part[t] = s;
    __syncthreads();
    if (t == 0) {
        unsigned cum = 0;
        int done = 0;
        for (int c = 255; c >= 0 && !done; --c) {
            if (cum + part[c] >= PRE) {
                for (int i = c * 8 + 7; i >= c * 8; --i) {
                    unsigned h = gh[i];
                    if (cum + h >= PRE) { bsel[img] = (unsigned)i; cntAbove[img] = cum; done = 1; break; }
                    cum += h;
                }
            } else {
                cum += part[c];
            }
        }
    }
}

// K3: histogram of next 11 bits within coarse bucket B (float4 loads)
__global__ void __launch_bounds__(256) k_hist2(const float4* __restrict__ obj4,
                                               const unsigned* __restrict__ bsel,
                                               unsigned* __restrict__ hist2) {
    __shared__ unsigned lh[NBUCKET];
    int img = blockIdx.y;
    unsigned B = bsel[img];
    for (int i = threadIdx.x; i < NBUCKET; i += 256) lh[i] = 0;
    __syncthreads();
    const float4* p = obj4 + (size_t)img * (AHW / 4);
    int stride = gridDim.x * 256;
    for (int v = blockIdx.x * 256 + threadIdx.x; v < AHW / 4; v += stride) {
        float4 f = p[v];
        unsigned m0 = mapf(f.x), m1 = mapf(f.y), m2 = mapf(f.z), m3 = mapf(f.w);
        if ((m0 >> 21) == B) atomicAdd(&lh[(m0 >> 10) & 0x7FF], 1u);
        if ((m1 >> 21) == B) atomicAdd(&lh[(m1 >> 10) & 0x7FF], 1u);
        if ((m2 >> 21) == B) atomicAdd(&lh[(m2 >> 10) & 0x7FF], 1u);
        if ((m3 >> 21) == B) atomicAdd(&lh[(m3 >> 10) & 0x7FF], 1u);
    }
    __syncthreads();
    unsigned* gh = hist2 + img * NBUCKET;
    for (int i = threadIdx.x; i < NBUCKET; i += 256)
        if (lh[i]) atomicAdd(&gh[i], lh[i]);
}

// K4: refine to 22-bit threshold
__global__ void __launch_bounds__(256) k_thresh2(const unsigned* __restrict__ hist2,
                                                 const unsigned* __restrict__ bsel,
                                                 const unsigned* __restrict__ cntAbove,
                                                 unsigned* __restrict__ thr32) {
    __shared__ unsigned part[256];
    int img = blockIdx.x;
    int t = threadIdx.x;
    const unsigned* gh = hist2 + img * NBUCKET;
    unsigned s = 0;
    for (int k = 0; k < 8; ++k) s += gh[t * 8 + k];
    part[t] = s;
    __syncthreads();
    if (t == 0) {
        unsigned cum = cntAbove[img];
        unsigned B = bsel[img];
        int done = 0;
        for (int c = 255; c >= 0 && !done; --c) {
            if (cum + part[c] >= PRE) {
                for (int i = c * 8 + 7; i >= c * 8; --i) {
                    unsigned h = gh[i];
                    if (cum + h >= PRE) { thr32[img] = (B << 21) | ((unsigned)i << 10); done = 1; break; }
                    cum += h;
                }
            } else {
                cum += part[c];
            }
        }
    }
}

// K5: compact candidates with m >= thr. Two-level: LDS staging + one global
// atomic per block (selcnt padded to a private cache line per image).
__global__ void __launch_bounds__(256) k_compact(const float4* __restrict__ obj4,
                                                 const unsigned* __restrict__ thr32,
                                                 unsigned* __restrict__ selcnt,
                                                 unsigned long long* __restrict__ keys) {
    __shared__ unsigned long long lbuf[LBUF];
    __shared__ unsigned lcnt, gbase;
    int img = blockIdx.y;
    unsigned thr = thr32[img];
    if (threadIdx.x == 0) lcnt = 0;
    __syncthreads();
    const float4* p = obj4 + (size_t)img * (AHW / 4);
    int v0 = blockIdx.x * 768;
    #pragma unroll
    for (int it = 0; it < 3; ++it) {
        int v = v0 + it * 256 + threadIdx.x;
        float4 f = p[v];
        int jb = v * 4;
        #pragma unroll
        for (int k = 0; k < 4; ++k) {
            float x = k == 0 ? f.x : (k == 1 ? f.y : (k == 2 ? f.z : f.w));
            unsigned m = mapf(x);
            if (m >= thr) {
                int j = jb + k;
                int a = j >> 16;
                int hw = j & 65535;
                unsigned idx = (unsigned)(hw * A + a);
                unsigned pos = atomicAdd(&lcnt, 1u);
                if (pos < LBUF)
                    lbuf[pos] = ((unsigned long long)m << 32) | (unsigned)(~idx);
            }
        }
    }
    __syncthreads();
    unsigned n = lcnt > LBUF ? LBUF : lcnt;
    if (threadIdx.x == 0) gbase = atomicAdd(&selcnt[img * 64], n);
    __syncthreads();
    if (threadIdx.x < n) {
        unsigned pos = gbase + threadIdx.x;
        if (pos < CAP2)
            keys[(size_t)img * CAP2 + pos] = lbuf[threadIdx.x];
    }
}

// K6: per-image bitonic sort, descending. Tail beyond the valid count is
// padded with 0 keys in LDS (keys buffer itself is not zeroed).
__global__ void __launch_bounds__(1024) k_sort(unsigned long long* __restrict__ keys,
                                               const unsigned* __restrict__ selcnt) {
    __shared__ unsigned long long s[CAP2];
    int img = blockIdx.x;
    unsigned cnt = selcnt[img * 64];
    if (cnt > CAP2) cnt = CAP2;
    unsigned long long* g = keys + (size_t)img * CAP2;
    for (int i = threadIdx.x; i < CAP2; i += 1024)
        s[i] = (i < (int)cnt) ? g[i] : 0ULL;
    __syncthreads();
    for (int k2 = 2; k2 <= CAP2; k2 <<= 1) {
        for (int j = k2 >> 1; j > 0; j >>= 1) {
            for (int i = threadIdx.x; i < CAP2; i += 1024) {
                int ixj = i ^ j;
                if (ixj > i) {
                    unsigned long long a = s[i], b = s[ixj];
                    bool up = ((i & k2) == 0);
                    if (up ? (a < b) : (a > b)) { s[i] = b; s[ixj] = a; }
                }
            }
            __syncthreads();
        }
    }
    for (int i = threadIdx.x; i < PRE; i += 1024) g[i] = s[i];
}

// K7: decode boxes (f64), clip, MIN_SIZE filter, sigmoid score.
// Writes f64 boxes (exact path) AND f32 boxes (screen path).
__global__ void k_decode(const float* __restrict__ anchors, const float* __restrict__ br,
                         const unsigned long long* __restrict__ keys,
                         double* __restrict__ boxes, float4* __restrict__ boxesf,
                         float* __restrict__ scores, unsigned* __restrict__ negmask) {
    int g = blockIdx.x * blockDim.x + threadIdx.x;
    if (g >= NIMG * PRE) return;
    int img = g / PRE, r = g % PRE;
    unsigned long long key = keys[(size_t)img * CAP2 + r];
    unsigned m = (unsigned)(key >> 32);
    unsigned idx = ~(unsigned)key;
    unsigned u = (m & 0x80000000u) ? (m ^ 0x80000000u) : ~m;
    float x = __uint_as_float(u);
    double sc = 1.0 / (1.0 + exp(-(double)x));
    int a = idx % 3;
    int hw = idx / 3;
    const float* anc = anchors + ((size_t)img * AHW + idx) * 4;
    double ax1 = anc[0], ay1 = anc[1], ax2 = anc[2], ay2 = anc[3];
    double aw = ax2 - ax1 + 1.0, ah = ay2 - ay1 + 1.0;
    double cx = ax1 + 0.5 * aw, cy = ay1 + 0.5 * ah;
    const float* bp = br + (size_t)img * 12 * HW + (size_t)a * 4 * HW + hw;
    double dx = bp[0];
    double dy = bp[(size_t)HW];
    double dw = bp[(size_t)2 * HW];
    double dh = bp[(size_t)3 * HW];
    const double CLIPV = 4.135166556742356; // log(1000/16)
    dw = fmin(dw, CLIPV); dh = fmin(dh, CLIPV);
    double pcx = dx * aw + cx, pcy = dy * ah + cy;
    double pw = exp(dw) * aw, ph = exp(dh) * ah;
    double x1 = pcx - 0.5 * pw, y1 = pcy - 0.5 * ph;
    double x2 = pcx + 0.5 * pw - 1.0, y2 = pcy + 0.5 * ph - 1.0;
    x1 = fmin(fmax(x1, 0.0), 1023.0);
    y1 = fmin(fmax(y1, 0.0), 1023.0);
    x2 = fmin(fmax(x2, 0.0), 1023.0);
    y2 = fmin(fmax(y2, 0.0), 1023.0);
    bool keep = (x2 - x1 + 1.0 >= 0.0) && (y2 - y1 + 1.0 >= 0.0);
    double* bo = boxes + ((size_t)img * PRE + r) * 4;
    bo[0] = x1; bo[1] = y1; bo[2] = x2; bo[3] = y2;
    float4 bf;
    bf.x = (float)x1; bf.y = (float)y1; bf.z = (float)x2; bf.w = (float)y2;
    boxesf[(size_t)img * PRE + r] = bf;
    scores[img * PRE + r] = keep ? (float)sc : NEGF;
    if (!keep) atomicOr(&negmask[img * 64 + (r >> 5)], 1u << (r & 31));
}

// K8: upper-triangle IoU suppression bitmask, f32 screen + exact f64 fallback
// for boundary pairs. 4 waves x 8 rows = 32 rows/block, f32 SoA + areas in LDS.
__global__ void __launch_bounds__(256) k_mask(const float4* __restrict__ boxesf,
                                              const double* __restrict__ boxes,
                                              unsigned* __restrict__ mask) {
    __shared__ float sx1[PRE], sy1[PRE], sx2[PRE], sy2[PRE], sar[PRE];
    int img = blockIdx.y;
    int tid = threadIdx.x;
    int wave = tid >> 6, t = tid & 63;
    const float4* fb = boxesf + (size_t)img * PRE;
    for (int i = tid; i < PRE; i += 256) {
        float4 b = fb[i];
        sx1[i] = b.x; sy1[i] = b.y; sx2[i] = b.z; sy2[i] = b.w;
        sar[i] = (b.z - b.x + 1.0f) * (b.w - b.y + 1.0f);
    }
    __syncthreads();
    const double* base64 = boxes + (size_t)img * PRE * 4;
    int rb = blockIdx.x * 32 + wave * 8;
    for (int rr = 0; rr < 8; ++rr) {
        int r = rb + rr;
        if (r >= PRE) break;
        float x1 = sx1[r], y1 = sy1[r], x2 = sx2[r], y2 = sy2[r];
        float ar = sar[r];
        int kmin = r >> 6;
        unsigned myw = 0;
        for (int k = kmin; k < 32; ++k) {
            int colr = 64 * k + t;
            int col = colr < PRE ? colr : PRE - 1;
            float bx1 = sx1[col], by1 = sy1[col], bx2 = sx2[col], by2 = sy2[col];
            float iw = fminf(x2, bx2) - fmaxf(x1, bx1) + 1.0f;
            float ih = fminf(y2, by2) - fmaxf(y1, by1) + 1.0f;
            bool res = false, need = false;
            if (iw > -BW && ih > -BW) {
                float inter = iw * ih;
                float un = (ar + sar[col]) - inter;
                float d = inter - 0.7f * un;
                need = (iw < BW) | (ih < BW) | (fabsf(d) < BD);
                res = d > 0.0f;
            }
            if (need) {
                // exact reference-formula recompute in f64 (rare)
                const double* ri = base64 + (size_t)r * 4;
                const double* rj = base64 + (size_t)col * 4;
                double X1 = ri[0], Y1 = ri[1], X2 = ri[2], Y2 = ri[3];
                double bX1 = rj[0], bY1 = rj[1], bX2 = rj[2], bY2 = rj[3];
                double IW = fmin(X2, bX2) - fmax(X1, bX1) + 1.0;
                double IH = fmin(Y2, bY2) - fmax(Y1, bY1) + 1.0;
                IW = IW > 0.0 ? IW : 0.0;
                IH = IH > 0.0 ? IH : 0.0;
                double INTER = IW * IH;
                double AR = (X2 - X1 + 1.0) * (Y2 - Y1 + 1.0);
                double AJ = (bX2 - bX1 + 1.0) * (bY2 - bY1 + 1.0);
                double IOU = INTER / ((AR + AJ) - INTER);
                res = IOU > 0.7;
            }
            res = res && (colr < PRE);
            unsigned long long bb = __ballot(res);
            if (t == 2 * k) myw = (unsigned)bb;
            if (t == 2 * k + 1) myw = (unsigned)(bb >> 32);
        }
        mask[((size_t)img * MROWS + r) * 64 + t] = myw;
    }
}

// K9: sequential-scan greedy NMS with 16-deep static prefetch ring.
__global__ void __launch_bounds__(64) k_nms(const double* __restrict__ boxes,
                                            const float* __restrict__ scores,
                                            const unsigned* __restrict__ negmask,
                                            const unsigned* __restrict__ mask,
                                            float* __restrict__ out) {
    __shared__ int picks[POST];
    int img = blockIdx.x;
    int t = threadIdx.x;
    unsigned sup = negmask[img * 64 + t];
    if (t == 62) sup |= 0xFFFF0000u;  // indices 2000..2015 invalid
    if (t == 63) sup = 0xFFFFFFFFu;   // indices 2016..2047 invalid
    const unsigned* mbase = mask + (size_t)img * MROWS * 64;
    unsigned rbuf[16];
    #pragma unroll
    for (int s = 0; s < 16; ++s) rbuf[s] = mbase[(size_t)s * 64 + t];
    int np = 0;
    for (int g = 0; g < PRE / 16; ++g) {
        #pragma unroll
        for (int s = 0; s < 16; ++s) {
            int jj = g * 16 + s;
            unsigned w = (unsigned)__builtin_amdgcn_readlane((int)sup, jj >> 5);
            bool alive = ((w >> (jj & 31)) & 1u) == 0u;
            unsigned r = rbuf[s];
            rbuf[s] = mbase[(size_t)(jj + 16) * 64 + t];  // rows padded to MROWS
            if (alive && np < POST) {
                sup |= r;
                if (t == 0) picks[np] = jj;
                np++;
            }
        }
        if (np >= POST) break;
    }
    __syncthreads();
    float* ob = out + (size_t)img * POST * 4;
    float* os = out + (size_t)NIMG * POST * 4 + (size_t)img * POST;
    for (int k = t; k < POST; k += 64) {
        if (k < np) {
            int p = picks[k];
            const double* bp = boxes + ((size_t)img * PRE + p) * 4;
            ob[k * 4 + 0] = (float)bp[0];
            ob[k * 4 + 1] = (float)bp[1];
            ob[k * 4 + 2] = (float)bp[2];
            ob[k * 4 + 3] = (float)bp[3];
            os[k] = scores[img * PRE + p];
        } else {
            ob[k * 4 + 0] = 0.0f; ob[k * 4 + 1] = 0.0f;
            ob[k * 4 + 2] = 0.0f; ob[k * 4 + 3] = 0.0f;
            os[k] = NEGF;
        }
    }
}

extern "C" void kernel_launch(void* const* d_in, const int* in_sizes, int n_in,
                              void* d_out, int out_size, void* d_ws, size_t ws_size,
                              hipStream_t stream) {
    const float* anchors = (const float*)d_in[0];
    const float4* obj4 = (const float4*)d_in[1];
    const float* br = (const float*)d_in[2];
    float* out = (float*)d_out;

    char* ws = (char*)d_ws;
    size_t off = 0;
    auto alloc = [&](size_t bytes) {
        void* p = ws + off;
        off = (off + bytes + 255) & ~(size_t)255;
        return p;
    };
    // zero-initialized region (single fused memset): hist..negmask
    unsigned* hist = (unsigned*)alloc((size_t)NIMG * NBUCKET * 4);
    unsigned* hist2 = (unsigned*)alloc((size_t)NIMG * NBUCKET * 4);
    unsigned* bsel = (unsigned*)alloc(NIMG * 4);
    unsigned* cntAbove = (unsigned*)alloc(NIMG * 4);
    unsigned* thr32 = (unsigned*)alloc(NIMG * 4);
    unsigned* selcnt = (unsigned*)alloc((size_t)NIMG * 64 * 4);      // one cache line per image
    unsigned* negmask = (unsigned*)alloc((size_t)NIMG * 64 * 4);
    size_t zero_bytes = off;
    // non-zeroed buffers
    unsigned long long* keys = (unsigned long long*)alloc((size_t)NIMG * CAP2 * 8);
    double* boxes = (double*)alloc((size_t)NIMG * PRE * 4 * 8);
    float4* boxesf = (float4*)alloc((size_t)NIMG * PRE * 16);
    float* scores = (float*)alloc((size_t)NIMG * PRE * 4);
    unsigned* mask = (unsigned*)alloc((size_t)NIMG * MROWS * 64 * 4);

    hipMemsetAsync(hist, 0, zero_bytes, stream);

    k_hist<<<dim3(64, NIMG), 256, 0, stream>>>(obj4, hist);
    k_thresh<<<NIMG, 256, 0, stream>>>(hist, bsel, cntAbove);
    k_hist2<<<dim3(64, NIMG), 256, 0, stream>>>(obj4, bsel, hist2);
    k_thresh2<<<NIMG, 256, 0, stream>>>(hist2, bsel, cntAbove, thr32);
    k_compact<<<dim3(64, NIMG), 256, 0, stream>>>(obj4, thr32, selcnt, keys);
    k_sort<<<NIMG, 1024, 0, stream>>>(keys, selcnt);
    k_decode<<<(NIMG * PRE + 255) / 256, 256, 0, stream>>>(anchors, br, keys, boxes, boxesf, scores, negmask);
    k_mask<<<dim3((PRE + 31) / 32, NIMG), 256, 0, stream>>>(boxesf, boxes, mask);
    k_nms<<<NIMG, 64, 0, stream>>>(boxes, scores, negmask, mask, out);
}

// Round 6
// 217.845 us; speedup vs baseline: 6.8468x; 1.0110x over previous
//
#include <hip/hip_runtime.h>
#include <math.h>

#define NIMG 16
#define A 3
#define HW 65536
#define AHW 196608
#define PRE 2000
#define POST 1000
#define CAP2 2048
#define MROWS 2048
#define NBUCKET 2048
#define NEGF (-1e30f)
#define LBUF 256
#define BW 0.01f
#define BD 4.0f

__device__ __forceinline__ unsigned mapf(float x) {
    unsigned u = __float_as_uint(x);
    return (u & 0x80000000u) ? ~u : (u | 0x80000000u);
}

// K1: per-image histogram of top 11 bits of monotone-mapped objectness (float4 loads)
__global__ void __launch_bounds__(256) k_hist(const float4* __restrict__ obj4,
                                              unsigned* __restrict__ hist) {
    __shared__ unsigned lh[NBUCKET];
    int img = blockIdx.y;
    for (int i = threadIdx.x; i < NBUCKET; i += 256) lh[i] = 0;
    __syncthreads();
    const float4* p = obj4 + (size_t)img * (AHW / 4);
    int stride = gridDim.x * 256;
    for (int v = blockIdx.x * 256 + threadIdx.x; v < AHW / 4; v += stride) {
        float4 f = p[v];
        atomicAdd(&lh[mapf(f.x) >> 21], 1u);
        atomicAdd(&lh[mapf(f.y) >> 21], 1u);
        atomicAdd(&lh[mapf(f.z) >> 21], 1u);
        atomicAdd(&lh[mapf(f.w) >> 21], 1u);
    }
    __syncthreads();
    unsigned* gh = hist + img * NBUCKET;
    for (int i = threadIdx.x; i < NBUCKET; i += 256)
        if (lh[i]) atomicAdd(&gh[i], lh[i]);
}

// K2: find coarse threshold bucket B per image; also count strictly above B
__global__ void __launch_bounds__(256) k_thresh(const unsigned* __restrict__ hist,
                                                unsigned* __restrict__ bsel,
                                                unsigned* __restrict__ cntAbove) {
    __shared__ unsigned part[256];
    int img = blockIdx.x;
    int t = threadIdx.x;
    const unsigned* gh = hist + img * NBUCKET;
    unsigned s = 0;
    for (int k = 0; k < 8; ++k) s += gh[t * 8 + k];
    part[t] = s;
    __syncthreads();
    if (t == 0) {
        unsigned cum = 0;
        int done = 0;
        for (int c = 255; c >= 0 && !done; --c) {
            if (cum + part[c] >= PRE) {
                for (int i = c * 8 + 7; i >= c * 8; --i) {
                    unsigned h = gh[i];
                    if (cum + h >= PRE) { bsel[img] = (unsigned)i; cntAbove[img] = cum; done = 1; break; }
                    cum += h;
                }
            } else {
                cum += part[c];
            }
        }
    }
}

// K3: histogram of next 11 bits within coarse bucket B (float4 loads)
__global__ void __launch_bounds__(256) k_hist2(const float4* __restrict__ obj4,
                                               const unsigned* __restrict__ bsel,
                                               unsigned* __restrict__ hist2) {
    __shared__ unsigned lh[NBUCKET];
    int img = blockIdx.y;
    unsigned B = bsel[img];
    for (int i = threadIdx.x; i < NBUCKET; i += 256) lh[i] = 0;
    __syncthreads();
    const float4* p = obj4 + (size_t)img * (AHW / 4);
    int stride = gridDim.x * 256;
    for (int v = blockIdx.x * 256 + threadIdx.x; v < AHW / 4; v += stride) {
        float4 f = p[v];
        unsigned m0 = mapf(f.x), m1 = mapf(f.y), m2 = mapf(f.z), m3 = mapf(f.w);
        if ((m0 >> 21) == B) atomicAdd(&lh[(m0 >> 10) & 0x7FF], 1u);
        if ((m1 >> 21) == B) atomicAdd(&lh[(m1 >> 10) & 0x7FF], 1u);
        if ((m2 >> 21) == B) atomicAdd(&lh[(m2 >> 10) & 0x7FF], 1u);
        if ((m3 >> 21) == B) atomicAdd(&lh[(m3 >> 10) & 0x7FF], 1u);
    }
    __syncthreads();
    unsigned* gh = hist2 + img * NBUCKET;
    for (int i = threadIdx.x; i < NBUCKET; i += 256)
        if (lh[i]) atomicAdd(&gh[i], lh[i]);
}

// K4: refine to 22-bit threshold
__global__ void __launch_bounds__(256) k_thresh2(const unsigned* __restrict__ hist2,
                                                 const unsigned* __restrict__ bsel,
                                                 const unsigned* __restrict__ cntAbove,
                                                 unsigned* __restrict__ thr32) {
    __shared__ unsigned part[256];
    int img = blockIdx.x;
    int t = threadIdx.x;
    const unsigned* gh = hist2 + img * NBUCKET;
    unsigned s = 0;
    for (int k = 0; k < 8; ++k) s += gh[t * 8 + k];
    part[t] = s;
    __syncthreads();
    if (t == 0) {
        unsigned cum = cntAbove[img];
        unsigned B = bsel[img];
        int done = 0;
        for (int c = 255; c >= 0 && !done; --c) {
            if (cum + part[c] >= PRE) {
                for (int i = c * 8 + 7; i >= c * 8; --i) {
                    unsigned h = gh[i];
                    if (cum + h >= PRE) { thr32[img] = (B << 21) | ((unsigned)i << 10); done = 1; break; }
                    cum += h;
                }
            } else {
                cum += part[c];
            }
        }
    }
}

// K5: compact candidates with m >= thr. Two-level: LDS staging + one global
// atomic per block (selcnt padded to a private cache line per image).
__global__ void __launch_bounds__(256) k_compact(const float4* __restrict__ obj4,
                                                 const unsigned* __restrict__ thr32,
                                                 unsigned* __restrict__ selcnt,
                                                 unsigned long long* __restrict__ keys) {
    __shared__ unsigned long long lbuf[LBUF];
    __shared__ unsigned lcnt, gbase;
    int img = blockIdx.y;
    unsigned thr = thr32[img];
    if (threadIdx.x == 0) lcnt = 0;
    __syncthreads();
    const float4* p = obj4 + (size_t)img * (AHW / 4);
    int v0 = blockIdx.x * 768;
    #pragma unroll
    for (int it = 0; it < 3; ++it) {
        int v = v0 + it * 256 + threadIdx.x;
        float4 f = p[v];
        int jb = v * 4;
        #pragma unroll
        for (int k = 0; k < 4; ++k) {
            float x = k == 0 ? f.x : (k == 1 ? f.y : (k == 2 ? f.z : f.w));
            unsigned m = mapf(x);
            if (m >= thr) {
                int j = jb + k;
                int a = j >> 16;
                int hw = j & 65535;
                unsigned idx = (unsigned)(hw * A + a);
                unsigned pos = atomicAdd(&lcnt, 1u);
                if (pos < LBUF)
                    lbuf[pos] = ((unsigned long long)m << 32) | (unsigned)(~idx);
            }
        }
    }
    __syncthreads();
    unsigned n = lcnt > LBUF ? LBUF : lcnt;
    if (threadIdx.x == 0) gbase = atomicAdd(&selcnt[img * 64], n);
    __syncthreads();
    if (threadIdx.x < n) {
        unsigned pos = gbase + threadIdx.x;
        if (pos < CAP2)
            keys[(size_t)img * CAP2 + pos] = lbuf[threadIdx.x];
    }
}

// K6: per-image bitonic sort, descending. Tail beyond the valid count is
// padded with 0 keys in LDS (keys buffer itself is not zeroed).
__global__ void __launch_bounds__(1024) k_sort(unsigned long long* __restrict__ keys,
                                               const unsigned* __restrict__ selcnt) {
    __shared__ unsigned long long s[CAP2];
    int img = blockIdx.x;
    unsigned cnt = selcnt[img * 64];
    if (cnt > CAP2) cnt = CAP2;
    unsigned long long* g = keys + (size_t)img * CAP2;
    for (int i = threadIdx.x; i < CAP2; i += 1024)
        s[i] = (i < (int)cnt) ? g[i] : 0ULL;
    __syncthreads();
    for (int k2 = 2; k2 <= CAP2; k2 <<= 1) {
        for (int j = k2 >> 1; j > 0; j >>= 1) {
            for (int i = threadIdx.x; i < CAP2; i += 1024) {
                int ixj = i ^ j;
                if (ixj > i) {
                    unsigned long long a = s[i], b = s[ixj];
                    bool up = ((i & k2) == 0);
                    if (up ? (a < b) : (a > b)) { s[i] = b; s[ixj] = a; }
                }
            }
            __syncthreads();
        }
    }
    for (int i = threadIdx.x; i < PRE; i += 1024) g[i] = s[i];
}

// K7: decode boxes (f64), clip, MIN_SIZE filter, sigmoid score.
// Writes f64 boxes (exact path) AND f32 boxes (screen path).
__global__ void k_decode(const float* __restrict__ anchors, const float* __restrict__ br,
                         const unsigned long long* __restrict__ keys,
                         double* __restrict__ boxes, float4* __restrict__ boxesf,
                         float* __restrict__ scores, unsigned* __restrict__ negmask) {
    int g = blockIdx.x * blockDim.x + threadIdx.x;
    if (g >= NIMG * PRE) return;
    int img = g / PRE, r = g % PRE;
    unsigned long long key = keys[(size_t)img * CAP2 + r];
    unsigned m = (unsigned)(key >> 32);
    unsigned idx = ~(unsigned)key;
    unsigned u = (m & 0x80000000u) ? (m ^ 0x80000000u) : ~m;
    float x = __uint_as_float(u);
    double sc = 1.0 / (1.0 + exp(-(double)x));
    int a = idx % 3;
    int hw = idx / 3;
    const float* anc = anchors + ((size_t)img * AHW + idx) * 4;
    double ax1 = anc[0], ay1 = anc[1], ax2 = anc[2], ay2 = anc[3];
    double aw = ax2 - ax1 + 1.0, ah = ay2 - ay1 + 1.0;
    double cx = ax1 + 0.5 * aw, cy = ay1 + 0.5 * ah;
    const float* bp = br + (size_t)img * 12 * HW + (size_t)a * 4 * HW + hw;
    double dx = bp[0];
    double dy = bp[(size_t)HW];
    double dw = bp[(size_t)2 * HW];
    double dh = bp[(size_t)3 * HW];
    const double CLIPV = 4.135166556742356; // log(1000/16)
    dw = fmin(dw, CLIPV); dh = fmin(dh, CLIPV);
    double pcx = dx * aw + cx, pcy = dy * ah + cy;
    double pw = exp(dw) * aw, ph = exp(dh) * ah;
    double x1 = pcx - 0.5 * pw, y1 = pcy - 0.5 * ph;
    double x2 = pcx + 0.5 * pw - 1.0, y2 = pcy + 0.5 * ph - 1.0;
    x1 = fmin(fmax(x1, 0.0), 1023.0);
    y1 = fmin(fmax(y1, 0.0), 1023.0);
    x2 = fmin(fmax(x2, 0.0), 1023.0);
    y2 = fmin(fmax(y2, 0.0), 1023.0);
    bool keep = (x2 - x1 + 1.0 >= 0.0) && (y2 - y1 + 1.0 >= 0.0);
    double* bo = boxes + ((size_t)img * PRE + r) * 4;
    bo[0] = x1; bo[1] = y1; bo[2] = x2; bo[3] = y2;
    float4 bf;
    bf.x = (float)x1; bf.y = (float)y1; bf.z = (float)x2; bf.w = (float)y2;
    boxesf[(size_t)img * PRE + r] = bf;
    scores[img * PRE + r] = keep ? (float)sc : NEGF;
    if (!keep) atomicOr(&negmask[img * 64 + (r >> 5)], 1u << (r & 31));
}

// K8: upper-triangle IoU suppression bitmask, f32 screen + exact f64 fallback
// for boundary pairs. 4 waves x 8 rows = 32 rows/block, f32 SoA + areas in LDS.
__global__ void __launch_bounds__(256) k_mask(const float4* __restrict__ boxesf,
                                              const double* __restrict__ boxes,
                                              unsigned* __restrict__ mask) {
    __shared__ float sx1[PRE], sy1[PRE], sx2[PRE], sy2[PRE], sar[PRE];
    int img = blockIdx.y;
    int tid = threadIdx.x;
    int wave = tid >> 6, t = tid & 63;
    const float4* fb = boxesf + (size_t)img * PRE;
    for (int i = tid; i < PRE; i += 256) {
        float4 b = fb[i];
        sx1[i] = b.x; sy1[i] = b.y; sx2[i] = b.z; sy2[i] = b.w;
        sar[i] = (b.z - b.x + 1.0f) * (b.w - b.y + 1.0f);
    }
    __syncthreads();
    const double* base64 = boxes + (size_t)img * PRE * 4;
    int rb = blockIdx.x * 32 + wave * 8;
    for (int rr = 0; rr < 8; ++rr) {
        int r = rb + rr;
        if (r >= PRE) break;
        float x1 = sx1[r], y1 = sy1[r], x2 = sx2[r], y2 = sy2[r];
        float ar = sar[r];
        int kmin = r >> 6;
        unsigned myw = 0;
        for (int k = kmin; k < 32; ++k) {
            int colr = 64 * k + t;
            int col = colr < PRE ? colr : PRE - 1;
            float bx1 = sx1[col], by1 = sy1[col], bx2 = sx2[col], by2 = sy2[col];
            float iw = fminf(x2, bx2) - fmaxf(x1, bx1) + 1.0f;
            float ih = fminf(y2, by2) - fmaxf(y1, by1) + 1.0f;
            bool res = false, need = false;
            if (iw > -BW && ih > -BW) {
                float inter = iw * ih;
                float un = (ar + sar[col]) - inter;
                float d = inter - 0.7f * un;
                need = (iw < BW) | (ih < BW) | (fabsf(d) < BD);
                res = d > 0.0f;
            }
            if (need) {
                // exact reference-formula recompute in f64 (rare)
                const double* ri = base64 + (size_t)r * 4;
                const double* rj = base64 + (size_t)col * 4;
                double X1 = ri[0], Y1 = ri[1], X2 = ri[2], Y2 = ri[3];
                double bX1 = rj[0], bY1 = rj[1], bX2 = rj[2], bY2 = rj[3];
                double IW = fmin(X2, bX2) - fmax(X1, bX1) + 1.0;
                double IH = fmin(Y2, bY2) - fmax(Y1, bY1) + 1.0;
                IW = IW > 0.0 ? IW : 0.0;
                IH = IH > 0.0 ? IH : 0.0;
                double INTER = IW * IH;
                double AR = (X2 - X1 + 1.0) * (Y2 - Y1 + 1.0);
                double AJ = (bX2 - bX1 + 1.0) * (bY2 - bY1 + 1.0);
                double IOU = INTER / ((AR + AJ) - INTER);
                res = IOU > 0.7;
            }
            res = res && (colr < PRE);
            unsigned long long bb = __ballot(res);
            if (t == 2 * k) myw = (unsigned)bb;
            if (t == 2 * k + 1) myw = (unsigned)(bb >> 32);
        }
        mask[((size_t)img * MROWS + r) * 64 + t] = myw;
    }
}

// K9: sequential-scan greedy NMS, 4-stage software pipeline (process group g
// from buffer p, immediately reload buffer p with group g+4) so the
// load->use distance is ~3 group bodies (~latency), removing the per-group
// memory stall the 16-deep ring suffered.
#define NMS_LOAD(B, G)                                          \
    _Pragma("unroll")                                           \
    for (int s = 0; s < 16; ++s) B[s] = mrow[((G) * 16 + s) * 64];

#define NMS_PROC(B, G)                                          \
    _Pragma("unroll")                                           \
    for (int s = 0; s < 16; ++s) {                              \
        int jj = (G) * 16 + s;                                  \
        unsigned w = (unsigned)__builtin_amdgcn_readlane((int)sup, jj >> 5); \
        bool alive = ((w >> (jj & 31)) & 1u) == 0u;             \
        if (alive && np < POST) {                               \
            sup |= B[s];                                        \
            if (t == 0) picks[np] = jj;                         \
            np++;                                               \
        }                                                       \
    }

__global__ void __launch_bounds__(64) k_nms(const double* __restrict__ boxes,
                                            const float* __restrict__ scores,
                                            const unsigned* __restrict__ negmask,
                                            const unsigned* __restrict__ mask,
                                            float* __restrict__ out) {
    __shared__ int picks[POST];
    int img = blockIdx.x;
    int t = threadIdx.x;
    unsigned sup = negmask[img * 64 + t];
    if (t == 62) sup |= 0xFFFF0000u;  // indices 2000..2015 invalid
    if (t == 63) sup = 0xFFFFFFFFu;   // indices 2016..2047 invalid
    const unsigned* mrow = mask + (size_t)img * MROWS * 64 + t;
    unsigned b0[16], b1[16], b2[16], b3[16];
    NMS_LOAD(b0, 0)
    NMS_LOAD(b1, 1)
    NMS_LOAD(b2, 2)
    NMS_LOAD(b3, 3)
    int np = 0;
    // 125 groups of 16 rows (2000). Main loop: groups 0..123; epilogue: 124.
    for (int gg = 0; gg < 124; gg += 4) {
        NMS_PROC(b0, gg + 0) NMS_LOAD(b0, gg + 4)
        NMS_PROC(b1, gg + 1) NMS_LOAD(b1, gg + 5)
        NMS_PROC(b2, gg + 2) NMS_LOAD(b2, gg + 6)
        NMS_PROC(b3, gg + 3) NMS_LOAD(b3, gg + 7)   // max load group 127 < MROWS/16
        if (np >= POST) break;
    }
    if (np < POST) { NMS_PROC(b0, 124) }
    __syncthreads();
    float* ob = out + (size_t)img * POST * 4;
    float* os = out + (size_t)NIMG * POST * 4 + (size_t)img * POST;
    for (int k = t; k < POST; k += 64) {
        if (k < np) {
            int p = picks[k];
            const double* bp = boxes + ((size_t)img * PRE + p) * 4;
            ob[k * 4 + 0] = (float)bp[0];
            ob[k * 4 + 1] = (float)bp[1];
            ob[k * 4 + 2] = (float)bp[2];
            ob[k * 4 + 3] = (float)bp[3];
            os[k] = scores[img * PRE + p];
        } else {
            ob[k * 4 + 0] = 0.0f; ob[k * 4 + 1] = 0.0f;
            ob[k * 4 + 2] = 0.0f; ob[k * 4 + 3] = 0.0f;
            os[k] = NEGF;
        }
    }
}

extern "C" void kernel_launch(void* const* d_in, const int* in_sizes, int n_in,
                              void* d_out, int out_size, void* d_ws, size_t ws_size,
                              hipStream_t stream) {
    const float* anchors = (const float*)d_in[0];
    const float4* obj4 = (const float4*)d_in[1];
    const float* br = (const float*)d_in[2];
    float* out = (float*)d_out;

    char* ws = (char*)d_ws;
    size_t off = 0;
    auto alloc = [&](size_t bytes) {
        void* p = ws + off;
        off = (off + bytes + 255) & ~(size_t)255;
        return p;
    };
    // zero-initialized region (single fused memset): hist..negmask
    unsigned* hist = (unsigned*)alloc((size_t)NIMG * NBUCKET * 4);
    unsigned* hist2 = (unsigned*)alloc((size_t)NIMG * NBUCKET * 4);
    unsigned* bsel = (unsigned*)alloc(NIMG * 4);
    unsigned* cntAbove = (unsigned*)alloc(NIMG * 4);
    unsigned* thr32 = (unsigned*)alloc(NIMG * 4);
    unsigned* selcnt = (unsigned*)alloc((size_t)NIMG * 64 * 4);      // one cache line per image
    unsigned* negmask = (unsigned*)alloc((size_t)NIMG * 64 * 4);
    size_t zero_bytes = off;
    // non-zeroed buffers
    unsigned long long* keys = (unsigned long long*)alloc((size_t)NIMG * CAP2 * 8);
    double* boxes = (double*)alloc((size_t)NIMG * PRE * 4 * 8);
    float4* boxesf = (float4*)alloc((size_t)NIMG * PRE * 16);
    float* scores = (float*)alloc((size_t)NIMG * PRE * 4);
    unsigned* mask = (unsigned*)alloc((size_t)NIMG * MROWS * 64 * 4);

    hipMemsetAsync(hist, 0, zero_bytes, stream);

    k_hist<<<dim3(64, NIMG), 256, 0, stream>>>(obj4, hist);
    k_thresh<<<NIMG, 256, 0, stream>>>(hist, bsel, cntAbove);
    k_hist2<<<dim3(64, NIMG), 256, 0, stream>>>(obj4, bsel, hist2);
    k_thresh2<<<NIMG, 256, 0, stream>>>(hist2, bsel, cntAbove, thr32);
    k_compact<<<dim3(64, NIMG), 256, 0, stream>>>(obj4, thr32, selcnt, keys);
    k_sort<<<NIMG, 1024, 0, stream>>>(keys, selcnt);
    k_decode<<<(NIMG * PRE + 255) / 256, 256, 0, stream>>>(anchors, br, keys, boxes, boxesf, scores, negmask);
    k_mask<<<dim3((PRE + 31) / 32, NIMG), 256, 0, stream>>>(boxesf, boxes, mask);
    k_nms<<<NIMG, 64, 0, stream>>>(boxes, scores, negmask, mask, out);
}

// Round 8
// 189.249 us; speedup vs baseline: 7.8813x; 1.1511x over previous
//
#include <hip/hip_runtime.h>
#include <math.h>

#define NIMG 16
#define A 3
#define HW 65536
#define AHW 196608
#define PRE 2000
#define POST 1000
#define CAP2 2048
#define MROWS 2048
#define NBUCKET 2048
#define NEGF (-1e30f)
#define LBUF 256
#define BW 0.01f
#define BD 4.0f

__device__ __forceinline__ unsigned mapf(float x) {
    unsigned u = __float_as_uint(x);
    return (u & 0x80000000u) ? ~u : (u | 0x80000000u);
}

// K1: per-image histogram of top 11 bits of monotone-mapped objectness (float4 loads)
__global__ void __launch_bounds__(256) k_hist(const float4* __restrict__ obj4,
                                              unsigned* __restrict__ hist) {
    __shared__ unsigned lh[NBUCKET];
    int img = blockIdx.y;
    for (int i = threadIdx.x; i < NBUCKET; i += 256) lh[i] = 0;
    __syncthreads();
    const float4* p = obj4 + (size_t)img * (AHW / 4);
    int stride = gridDim.x * 256;
    for (int v = blockIdx.x * 256 + threadIdx.x; v < AHW / 4; v += stride) {
        float4 f = p[v];
        atomicAdd(&lh[mapf(f.x) >> 21], 1u);
        atomicAdd(&lh[mapf(f.y) >> 21], 1u);
        atomicAdd(&lh[mapf(f.z) >> 21], 1u);
        atomicAdd(&lh[mapf(f.w) >> 21], 1u);
    }
    __syncthreads();
    unsigned* gh = hist + img * NBUCKET;
    for (int i = threadIdx.x; i < NBUCKET; i += 256)
        if (lh[i]) atomicAdd(&gh[i], lh[i]);
}

// K2: find coarse threshold bucket B per image; also count strictly above B
__global__ void __launch_bounds__(256) k_thresh(const unsigned* __restrict__ hist,
                                                unsigned* __restrict__ bsel,
                                                unsigned* __restrict__ cntAbove) {
    __shared__ unsigned part[256];
    int img = blockIdx.x;
    int t = threadIdx.x;
    const unsigned* gh = hist + img * NBUCKET;
    unsigned s = 0;
    for (int k = 0; k < 8; ++k) s += gh[t * 8 + k];
    part[t] = s;
    __syncthreads();
    if (t == 0) {
        unsigned cum = 0;
        int done = 0;
        for (int c = 255; c >= 0 && !done; --c) {
            if (cum + part[c] >= PRE) {
                for (int i = c * 8 + 7; i >= c * 8; --i) {
                    unsigned h = gh[i];
                    if (cum + h >= PRE) { bsel[img] = (unsigned)i; cntAbove[img] = cum; done = 1; break; }
                    cum += h;
                }
            } else {
                cum += part[c];
            }
        }
    }
}

// K3: histogram of next 11 bits within coarse bucket B (float4 loads)
__global__ void __launch_bounds__(256) k_hist2(const float4* __restrict__ obj4,
                                               const unsigned* __restrict__ bsel,
                                               unsigned* __restrict__ hist2) {
    __shared__ unsigned lh[NBUCKET];
    int img = blockIdx.y;
    unsigned B = bsel[img];
    for (int i = threadIdx.x; i < NBUCKET; i += 256) lh[i] = 0;
    __syncthreads();
    const float4* p = obj4 + (size_t)img * (AHW / 4);
    int stride = gridDim.x * 256;
    for (int v = blockIdx.x * 256 + threadIdx.x; v < AHW / 4; v += stride) {
        float4 f = p[v];
        unsigned m0 = mapf(f.x), m1 = mapf(f.y), m2 = mapf(f.z), m3 = mapf(f.w);
        if ((m0 >> 21) == B) atomicAdd(&lh[(m0 >> 10) & 0x7FF], 1u);
        if ((m1 >> 21) == B) atomicAdd(&lh[(m1 >> 10) & 0x7FF], 1u);
        if ((m2 >> 21) == B) atomicAdd(&lh[(m2 >> 10) & 0x7FF], 1u);
        if ((m3 >> 21) == B) atomicAdd(&lh[(m3 >> 10) & 0x7FF], 1u);
    }
    __syncthreads();
    unsigned* gh = hist2 + img * NBUCKET;
    for (int i = threadIdx.x; i < NBUCKET; i += 256)
        if (lh[i]) atomicAdd(&gh[i], lh[i]);
}

// K4: refine to 22-bit threshold
__global__ void __launch_bounds__(256) k_thresh2(const unsigned* __restrict__ hist2,
                                                 const unsigned* __restrict__ bsel,
                                                 const unsigned* __restrict__ cntAbove,
                                                 unsigned* __restrict__ thr32) {
    __shared__ unsigned part[256];
    int img = blockIdx.x;
    int t = threadIdx.x;
    const unsigned* gh = hist2 + img * NBUCKET;
    unsigned s = 0;
    for (int k = 0; k < 8; ++k) s += gh[t * 8 + k];
    part[t] = s;
    __syncthreads();
    if (t == 0) {
        unsigned cum = cntAbove[img];
        unsigned B = bsel[img];
        int done = 0;
        for (int c = 255; c >= 0 && !done; --c) {
            if (cum + part[c] >= PRE) {
                for (int i = c * 8 + 7; i >= c * 8; --i) {
                    unsigned h = gh[i];
                    if (cum + h >= PRE) { thr32[img] = (B << 21) | ((unsigned)i << 10); done = 1; break; }
                    cum += h;
                }
            } else {
                cum += part[c];
            }
        }
    }
}

// K5: compact candidates with m >= thr. Two-level: LDS staging + one global
// atomic per block (selcnt padded to a private cache line per image).
__global__ void __launch_bounds__(256) k_compact(const float4* __restrict__ obj4,
                                                 const unsigned* __restrict__ thr32,
                                                 unsigned* __restrict__ selcnt,
                                                 unsigned long long* __restrict__ keys) {
    __shared__ unsigned long long lbuf[LBUF];
    __shared__ unsigned lcnt, gbase;
    int img = blockIdx.y;
    unsigned thr = thr32[img];
    if (threadIdx.x == 0) lcnt = 0;
    __syncthreads();
    const float4* p = obj4 + (size_t)img * (AHW / 4);
    int v0 = blockIdx.x * 768;
    #pragma unroll
    for (int it = 0; it < 3; ++it) {
        int v = v0 + it * 256 + threadIdx.x;
        float4 f = p[v];
        int jb = v * 4;
        #pragma unroll
        for (int k = 0; k < 4; ++k) {
            float x = k == 0 ? f.x : (k == 1 ? f.y : (k == 2 ? f.z : f.w));
            unsigned m = mapf(x);
            if (m >= thr) {
                int j = jb + k;
                int a = j >> 16;
                int hw = j & 65535;
                unsigned idx = (unsigned)(hw * A + a);
                unsigned pos = atomicAdd(&lcnt, 1u);
                if (pos < LBUF)
                    lbuf[pos] = ((unsigned long long)m << 32) | (unsigned)(~idx);
            }
        }
    }
    __syncthreads();
    unsigned n = lcnt > LBUF ? LBUF : lcnt;
    if (threadIdx.x == 0) gbase = atomicAdd(&selcnt[img * 64], n);
    __syncthreads();
    if (threadIdx.x < n) {
        unsigned pos = gbase + threadIdx.x;
        if (pos < CAP2)
            keys[(size_t)img * CAP2 + pos] = lbuf[threadIdx.x];
    }
}

// K6: per-image bitonic sort, descending. Tail beyond the valid count is
// padded with 0 keys in LDS (keys buffer itself is not zeroed).
__global__ void __launch_bounds__(1024) k_sort(unsigned long long* __restrict__ keys,
                                               const unsigned* __restrict__ selcnt) {
    __shared__ unsigned long long s[CAP2];
    int img = blockIdx.x;
    unsigned cnt = selcnt[img * 64];
    if (cnt > CAP2) cnt = CAP2;
    unsigned long long* g = keys + (size_t)img * CAP2;
    for (int i = threadIdx.x; i < CAP2; i += 1024)
        s[i] = (i < (int)cnt) ? g[i] : 0ULL;
    __syncthreads();
    for (int k2 = 2; k2 <= CAP2; k2 <<= 1) {
        for (int j = k2 >> 1; j > 0; j >>= 1) {
            for (int i = threadIdx.x; i < CAP2; i += 1024) {
                int ixj = i ^ j;
                if (ixj > i) {
                    unsigned long long a = s[i], b = s[ixj];
                    bool up = ((i & k2) == 0);
                    if (up ? (a < b) : (a > b)) { s[i] = b; s[ixj] = a; }
                }
            }
            __syncthreads();
        }
    }
    for (int i = threadIdx.x; i < PRE; i += 1024) g[i] = s[i];
}

// K7: decode boxes (f64), clip, MIN_SIZE filter, sigmoid score.
// Writes f64 boxes (exact path) AND f32 boxes (screen path).
__global__ void k_decode(const float* __restrict__ anchors, const float* __restrict__ br,
                         const unsigned long long* __restrict__ keys,
                         double* __restrict__ boxes, float4* __restrict__ boxesf,
                         float* __restrict__ scores, unsigned* __restrict__ negmask) {
    int g = blockIdx.x * blockDim.x + threadIdx.x;
    if (g >= NIMG * PRE) return;
    int img = g / PRE, r = g % PRE;
    unsigned long long key = keys[(size_t)img * CAP2 + r];
    unsigned m = (unsigned)(key >> 32);
    unsigned idx = ~(unsigned)key;
    unsigned u = (m & 0x80000000u) ? (m ^ 0x80000000u) : ~m;
    float x = __uint_as_float(u);
    double sc = 1.0 / (1.0 + exp(-(double)x));
    int a = idx % 3;
    int hw = idx / 3;
    const float* anc = anchors + ((size_t)img * AHW + idx) * 4;
    double ax1 = anc[0], ay1 = anc[1], ax2 = anc[2], ay2 = anc[3];
    double aw = ax2 - ax1 + 1.0, ah = ay2 - ay1 + 1.0;
    double cx = ax1 + 0.5 * aw, cy = ay1 + 0.5 * ah;
    const float* bp = br + (size_t)img * 12 * HW + (size_t)a * 4 * HW + hw;
    double dx = bp[0];
    double dy = bp[(size_t)HW];
    double dw = bp[(size_t)2 * HW];
    double dh = bp[(size_t)3 * HW];
    const double CLIPV = 4.135166556742356; // log(1000/16)
    dw = fmin(dw, CLIPV); dh = fmin(dh, CLIPV);
    double pcx = dx * aw + cx, pcy = dy * ah + cy;
    double pw = exp(dw) * aw, ph = exp(dh) * ah;
    double x1 = pcx - 0.5 * pw, y1 = pcy - 0.5 * ph;
    double x2 = pcx + 0.5 * pw - 1.0, y2 = pcy + 0.5 * ph - 1.0;
    x1 = fmin(fmax(x1, 0.0), 1023.0);
    y1 = fmin(fmax(y1, 0.0), 1023.0);
    x2 = fmin(fmax(x2, 0.0), 1023.0);
    y2 = fmin(fmax(y2, 0.0), 1023.0);
    bool keep = (x2 - x1 + 1.0 >= 0.0) && (y2 - y1 + 1.0 >= 0.0);
    double* bo = boxes + ((size_t)img * PRE + r) * 4;
    bo[0] = x1; bo[1] = y1; bo[2] = x2; bo[3] = y2;
    float4 bf;
    bf.x = (float)x1; bf.y = (float)y1; bf.z = (float)x2; bf.w = (float)y2;
    boxesf[(size_t)img * PRE + r] = bf;
    scores[img * PRE + r] = keep ? (float)sc : NEGF;
    if (!keep) atomicOr(&negmask[img * 64 + (r >> 5)], 1u << (r & 31));
}

// K8: upper-triangle IoU suppression bitmask, f32 screen + exact f64 fallback
// for boundary pairs. 4 waves x 8 rows = 32 rows/block, f32 SoA + areas in LDS.
__global__ void __launch_bounds__(256) k_mask(const float4* __restrict__ boxesf,
                                              const double* __restrict__ boxes,
                                              unsigned* __restrict__ mask) {
    __shared__ float sx1[PRE], sy1[PRE], sx2[PRE], sy2[PRE], sar[PRE];
    int img = blockIdx.y;
    int tid = threadIdx.x;
    int wave = tid >> 6, t = tid & 63;
    const float4* fb = boxesf + (size_t)img * PRE;
    for (int i = tid; i < PRE; i += 256) {
        float4 b = fb[i];
        sx1[i] = b.x; sy1[i] = b.y; sx2[i] = b.z; sy2[i] = b.w;
        sar[i] = (b.z - b.x + 1.0f) * (b.w - b.y + 1.0f);
    }
    __syncthreads();
    const double* base64 = boxes + (size_t)img * PRE * 4;
    int rb = blockIdx.x * 32 + wave * 8;
    for (int rr = 0; rr < 8; ++rr) {
        int r = rb + rr;
        if (r >= PRE) break;
        float x1 = sx1[r], y1 = sy1[r], x2 = sx2[r], y2 = sy2[r];
        float ar = sar[r];
        int kmin = r >> 6;
        unsigned myw = 0;
        for (int k = kmin; k < 32; ++k) {
            int colr = 64 * k + t;
            int col = colr < PRE ? colr : PRE - 1;
            float bx1 = sx1[col], by1 = sy1[col], bx2 = sx2[col], by2 = sy2[col];
            float iw = fminf(x2, bx2) - fmaxf(x1, bx1) + 1.0f;
            float ih = fminf(y2, by2) - fmaxf(y1, by1) + 1.0f;
            bool res = false, need = false;
            if (iw > -BW && ih > -BW) {
                float inter = iw * ih;
                float un = (ar + sar[col]) - inter;
                float d = inter - 0.7f * un;
                need = (iw < BW) | (ih < BW) | (fabsf(d) < BD);
                res = d > 0.0f;
            }
            if (need) {
                // exact reference-formula recompute in f64 (rare)
                const double* ri = base64 + (size_t)r * 4;
                const double* rj = base64 + (size_t)col * 4;
                double X1 = ri[0], Y1 = ri[1], X2 = ri[2], Y2 = ri[3];
                double bX1 = rj[0], bY1 = rj[1], bX2 = rj[2], bY2 = rj[3];
                double IW = fmin(X2, bX2) - fmax(X1, bX1) + 1.0;
                double IH = fmin(Y2, bY2) - fmax(Y1, bY1) + 1.0;
                IW = IW > 0.0 ? IW : 0.0;
                IH = IH > 0.0 ? IH : 0.0;
                double INTER = IW * IH;
                double AR = (X2 - X1 + 1.0) * (Y2 - Y1 + 1.0);
                double AJ = (bX2 - bX1 + 1.0) * (bY2 - bY1 + 1.0);
                double IOU = INTER / ((AR + AJ) - INTER);
                res = IOU > 0.7;
            }
            res = res && (colr < PRE);
            unsigned long long bb = __ballot(res);
            if (t == 2 * k) myw = (unsigned)bb;
            if (t == 2 * k + 1) myw = (unsigned)(bb >> 32);
        }
        mask[((size_t)img * MROWS + r) * 64 + t] = myw;
    }
}

// K9: sequential-scan greedy NMS, branchless scalar-mirror inner loop.
// s_cur (SGPR) mirrors the current 32-index word of sup; per iteration the
// whole update is straight-line SALU (bit test -> mask -> OR), the vector
// sup update is 2 VALU, and picks are recorded as a wave-uniform bitmap
// deposited into lane W of pickedv via a branchless select (writelane has
// no builtin on gfx950). Recording picks beyond POST is harmless: the
// epilogue truncates in index order, which equals pick order.
#define NMS_LOAD(B, G)                                          \
    _Pragma("unroll")                                           \
    for (int s = 0; s < 16; ++s) B[s] = mrow[((G) * 16 + s) * 64];

#define NMS_PROC(B, G, PAR) {                                   \
    int W = (G) >> 1;                                           \
    if ((PAR) == 0) s_cur = (unsigned)__builtin_amdgcn_readlane((int)sup, W); \
    _Pragma("unroll")                                           \
    for (int s = 0; s < 16; ++s) {                              \
        unsigned rb = (unsigned)__builtin_amdgcn_readlane((int)B[s], W); \
        unsigned bit = (s_cur >> (((PAR) << 4) + s)) & 1u;      \
        unsigned am = bit - 1u;  /* alive: ~0, dead: 0 */       \
        s_cur |= rb & am;                                       \
        s_pick |= am & (1u << (((PAR) << 4) + s));              \
        sup |= B[s] & am;                                       \
    }                                                           \
    if ((PAR) == 1) {                                           \
        pickedv = (t == W) ? (int)s_pick : pickedv;             \
        np += __builtin_popcount(s_pick);                       \
        s_pick = 0;                                             \
    }                                                           \
}

__global__ void __launch_bounds__(64) k_nms(const double* __restrict__ boxes,
                                            const float* __restrict__ scores,
                                            const unsigned* __restrict__ negmask,
                                            const unsigned* __restrict__ mask,
                                            float* __restrict__ out) {
    __shared__ int picks[POST];
    __shared__ unsigned wcnt[64];
    __shared__ int tot;
    int img = blockIdx.x;
    int t = threadIdx.x;
    unsigned sup = negmask[img * 64 + t];
    if (t == 62) sup |= 0xFFFF0000u;  // indices 2000..2015 invalid
    if (t == 63) sup = 0xFFFFFFFFu;   // indices 2016..2047 invalid
    const unsigned* mrow = mask + (size_t)img * MROWS * 64 + t;
    unsigned b0[16], b1[16], b2[16], b3[16];
    NMS_LOAD(b0, 0)
    NMS_LOAD(b1, 1)
    NMS_LOAD(b2, 2)
    NMS_LOAD(b3, 3)
    int np = 0;
    unsigned s_cur = 0, s_pick = 0;
    int pickedv = 0;
    // 125 groups of 16 rows (2000). Main loop: groups 0..123; epilogue: 124.
    for (int gg = 0; gg < 124; gg += 4) {
        NMS_PROC(b0, gg + 0, 0) NMS_LOAD(b0, gg + 4)
        NMS_PROC(b1, gg + 1, 1) NMS_LOAD(b1, gg + 5)
        NMS_PROC(b2, gg + 2, 0) NMS_LOAD(b2, gg + 6)
        NMS_PROC(b3, gg + 3, 1) NMS_LOAD(b3, gg + 7)   // max load group 127 < MROWS/16
        if (np >= POST) break;
    }
    if (np < POST) {
        NMS_PROC(b0, 124, 0)   // jj 1984..1999, word 62 low half
        pickedv = (t == 62) ? (int)s_pick : pickedv;
        np += __builtin_popcount(s_pick);
    }
    // epilogue: materialize picks[] from the bitmap (lane W holds word W)
    wcnt[t] = (unsigned)__builtin_popcount((unsigned)pickedv);
    __syncthreads();
    int pre = 0;
    for (int i = 0; i < t; ++i) pre += (int)wcnt[i];
    if (t == 63) tot = pre + (int)wcnt[63];
    __syncthreads();
    unsigned pw = (unsigned)pickedv;
    int rank = pre;
    while (pw) {
        int b = __ffs(pw) - 1;
        pw &= pw - 1;
        if (rank < POST) picks[rank] = t * 32 + b;
        rank++;
    }
    __syncthreads();
    int np_final = tot > POST ? POST : tot;
    float* ob = out + (size_t)img * POST * 4;
    float* os = out + (size_t)NIMG * POST * 4 + (size_t)img * POST;
    for (int k = t; k < POST; k += 64) {
        if (k < np_final) {
            int p = picks[k];
            const double* bp = boxes + ((size_t)img * PRE + p) * 4;
            ob[k * 4 + 0] = (float)bp[0];
            ob[k * 4 + 1] = (float)bp[1];
            ob[k * 4 + 2] = (float)bp[2];
            ob[k * 4 + 3] = (float)bp[3];
            os[k] = scores[img * PRE + p];
        } else {
            ob[k * 4 + 0] = 0.0f; ob[k * 4 + 1] = 0.0f;
            ob[k * 4 + 2] = 0.0f; ob[k * 4 + 3] = 0.0f;
            os[k] = NEGF;
        }
    }
}

extern "C" void kernel_launch(void* const* d_in, const int* in_sizes, int n_in,
                              void* d_out, int out_size, void* d_ws, size_t ws_size,
                              hipStream_t stream) {
    const float* anchors = (const float*)d_in[0];
    const float4* obj4 = (const float4*)d_in[1];
    const float* br = (const float*)d_in[2];
    float* out = (float*)d_out;

    char* ws = (char*)d_ws;
    size_t off = 0;
    auto alloc = [&](size_t bytes) {
        void* p = ws + off;
        off = (off + bytes + 255) & ~(size_t)255;
        return p;
    };
    // zero-initialized region (single fused memset): hist..negmask
    unsigned* hist = (unsigned*)alloc((size_t)NIMG * NBUCKET * 4);
    unsigned* hist2 = (unsigned*)alloc((size_t)NIMG * NBUCKET * 4);
    unsigned* bsel = (unsigned*)alloc(NIMG * 4);
    unsigned* cntAbove = (unsigned*)alloc(NIMG * 4);
    unsigned* thr32 = (unsigned*)alloc(NIMG * 4);
    unsigned* selcnt = (unsigned*)alloc((size_t)NIMG * 64 * 4);      // one cache line per image
    unsigned* negmask = (unsigned*)alloc((size_t)NIMG * 64 * 4);
    size_t zero_bytes = off;
    // non-zeroed buffers
    unsigned long long* keys = (unsigned long long*)alloc((size_t)NIMG * CAP2 * 8);
    double* boxes = (double*)alloc((size_t)NIMG * PRE * 4 * 8);
    float4* boxesf = (float4*)alloc((size_t)NIMG * PRE * 16);
    float* scores = (float*)alloc((size_t)NIMG * PRE * 4);
    unsigned* mask = (unsigned*)alloc((size_t)NIMG * MROWS * 64 * 4);

    hipMemsetAsync(hist, 0, zero_bytes, stream);

    k_hist<<<dim3(16, NIMG), 256, 0, stream>>>(obj4, hist);
    k_thresh<<<NIMG, 256, 0, stream>>>(hist, bsel, cntAbove);
    k_hist2<<<dim3(16, NIMG), 256, 0, stream>>>(obj4, bsel, hist2);
    k_thresh2<<<NIMG, 256, 0, stream>>>(hist2, bsel, cntAbove, thr32);
    k_compact<<<dim3(64, NIMG), 256, 0, stream>>>(obj4, thr32, selcnt, keys);
    k_sort<<<NIMG, 1024, 0, stream>>>(keys, selcnt);
    k_decode<<<(NIMG * PRE + 255) / 256, 256, 0, stream>>>(anchors, br, keys, boxes, boxesf, scores, negmask);
    k_mask<<<dim3((PRE + 31) / 32, NIMG), 256, 0, stream>>>(boxesf, boxes, mask);
    k_nms<<<NIMG, 64, 0, stream>>>(boxes, scores, negmask, mask, out);
}

// Round 9
// 182.069 us; speedup vs baseline: 8.1922x; 1.0394x over previous
//
#include <hip/hip_runtime.h>
#include <math.h>

#define NIMG 16
#define A 3
#define HW 65536
#define AHW 196608
#define PRE 2000
#define POST 1000
#define CAP2 2048
#define MROWS 2048
#define NBUCKET 2048
#define NEGF (-1e30f)
#define LBUF 256
#define BW 0.01f
#define BD 4.0f
#define MBLK 63

__device__ __forceinline__ unsigned mapf(float x) {
    unsigned u = __float_as_uint(x);
    return (u & 0x80000000u) ? ~u : (u | 0x80000000u);
}

// K1: per-image histogram of top 11 bits of monotone-mapped objectness (float4 loads)
__global__ void __launch_bounds__(256) k_hist(const float4* __restrict__ obj4,
                                              unsigned* __restrict__ hist) {
    __shared__ unsigned lh[NBUCKET];
    int img = blockIdx.y;
    for (int i = threadIdx.x; i < NBUCKET; i += 256) lh[i] = 0;
    __syncthreads();
    const float4* p = obj4 + (size_t)img * (AHW / 4);
    int stride = gridDim.x * 256;
    for (int v = blockIdx.x * 256 + threadIdx.x; v < AHW / 4; v += stride) {
        float4 f = p[v];
        atomicAdd(&lh[mapf(f.x) >> 21], 1u);
        atomicAdd(&lh[mapf(f.y) >> 21], 1u);
        atomicAdd(&lh[mapf(f.z) >> 21], 1u);
        atomicAdd(&lh[mapf(f.w) >> 21], 1u);
    }
    __syncthreads();
    unsigned* gh = hist + img * NBUCKET;
    for (int i = threadIdx.x; i < NBUCKET; i += 256)
        if (lh[i]) atomicAdd(&gh[i], lh[i]);
}

// K2: find coarse threshold bucket B per image; also count strictly above B
__global__ void __launch_bounds__(256) k_thresh(const unsigned* __restrict__ hist,
                                                unsigned* __restrict__ bsel,
                                                unsigned* __restrict__ cntAbove) {
    __shared__ unsigned part[256];
    int img = blockIdx.x;
    int t = threadIdx.x;
    const unsigned* gh = hist + img * NBUCKET;
    unsigned s = 0;
    for (int k = 0; k < 8; ++k) s += gh[t * 8 + k];
    part[t] = s;
    __syncthreads();
    if (t == 0) {
        unsigned cum = 0;
        int done = 0;
        for (int c = 255; c >= 0 && !done; --c) {
            if (cum + part[c] >= PRE) {
                for (int i = c * 8 + 7; i >= c * 8; --i) {
                    unsigned h = gh[i];
                    if (cum + h >= PRE) { bsel[img] = (unsigned)i; cntAbove[img] = cum; done = 1; break; }
                    cum += h;
                }
            } else {
                cum += part[c];
            }
        }
    }
}

// K3: histogram of next 11 bits within coarse bucket B (float4 loads)
__global__ void __launch_bounds__(256) k_hist2(const float4* __restrict__ obj4,
                                               const unsigned* __restrict__ bsel,
                                               unsigned* __restrict__ hist2) {
    __shared__ unsigned lh[NBUCKET];
    int img = blockIdx.y;
    unsigned B = bsel[img];
    for (int i = threadIdx.x; i < NBUCKET; i += 256) lh[i] = 0;
    __syncthreads();
    const float4* p = obj4 + (size_t)img * (AHW / 4);
    int stride = gridDim.x * 256;
    for (int v = blockIdx.x * 256 + threadIdx.x; v < AHW / 4; v += stride) {
        float4 f = p[v];
        unsigned m0 = mapf(f.x), m1 = mapf(f.y), m2 = mapf(f.z), m3 = mapf(f.w);
        if ((m0 >> 21) == B) atomicAdd(&lh[(m0 >> 10) & 0x7FF], 1u);
        if ((m1 >> 21) == B) atomicAdd(&lh[(m1 >> 10) & 0x7FF], 1u);
        if ((m2 >> 21) == B) atomicAdd(&lh[(m2 >> 10) & 0x7FF], 1u);
        if ((m3 >> 21) == B) atomicAdd(&lh[(m3 >> 10) & 0x7FF], 1u);
    }
    __syncthreads();
    unsigned* gh = hist2 + img * NBUCKET;
    for (int i = threadIdx.x; i < NBUCKET; i += 256)
        if (lh[i]) atomicAdd(&gh[i], lh[i]);
}

// K4: refine to 22-bit threshold
__global__ void __launch_bounds__(256) k_thresh2(const unsigned* __restrict__ hist2,
                                                 const unsigned* __restrict__ bsel,
                                                 const unsigned* __restrict__ cntAbove,
                                                 unsigned* __restrict__ thr32) {
    __shared__ unsigned part[256];
    int img = blockIdx.x;
    int t = threadIdx.x;
    const unsigned* gh = hist2 + img * NBUCKET;
    unsigned s = 0;
    for (int k = 0; k < 8; ++k) s += gh[t * 8 + k];
    part[t] = s;
    __syncthreads();
    if (t == 0) {
        unsigned cum = cntAbove[img];
        unsigned B = bsel[img];
        int done = 0;
        for (int c = 255; c >= 0 && !done; --c) {
            if (cum + part[c] >= PRE) {
                for (int i = c * 8 + 7; i >= c * 8; --i) {
                    unsigned h = gh[i];
                    if (cum + h >= PRE) { thr32[img] = (B << 21) | ((unsigned)i << 10); done = 1; break; }
                    cum += h;
                }
            } else {
                cum += part[c];
            }
        }
    }
}

// K5: compact candidates with m >= thr. Two-level: LDS staging + one global
// atomic per block (selcnt padded to a private cache line per image).
__global__ void __launch_bounds__(256) k_compact(const float4* __restrict__ obj4,
                                                 const unsigned* __restrict__ thr32,
                                                 unsigned* __restrict__ selcnt,
                                                 unsigned long long* __restrict__ keys) {
    __shared__ unsigned long long lbuf[LBUF];
    __shared__ unsigned lcnt, gbase;
    int img = blockIdx.y;
    unsigned thr = thr32[img];
    if (threadIdx.x == 0) lcnt = 0;
    __syncthreads();
    const float4* p = obj4 + (size_t)img * (AHW / 4);
    int v0 = blockIdx.x * 768;
    #pragma unroll
    for (int it = 0; it < 3; ++it) {
        int v = v0 + it * 256 + threadIdx.x;
        float4 f = p[v];
        int jb = v * 4;
        #pragma unroll
        for (int k = 0; k < 4; ++k) {
            float x = k == 0 ? f.x : (k == 1 ? f.y : (k == 2 ? f.z : f.w));
            unsigned m = mapf(x);
            if (m >= thr) {
                int j = jb + k;
                int a = j >> 16;
                int hw = j & 65535;
                unsigned idx = (unsigned)(hw * A + a);
                unsigned pos = atomicAdd(&lcnt, 1u);
                if (pos < LBUF)
                    lbuf[pos] = ((unsigned long long)m << 32) | (unsigned)(~idx);
            }
        }
    }
    __syncthreads();
    unsigned n = lcnt > LBUF ? LBUF : lcnt;
    if (threadIdx.x == 0) gbase = atomicAdd(&selcnt[img * 64], n);
    __syncthreads();
    if (threadIdx.x < n) {
        unsigned pos = gbase + threadIdx.x;
        if (pos < CAP2)
            keys[(size_t)img * CAP2 + pos] = lbuf[threadIdx.x];
    }
}

// K6: per-image bitonic sort, descending. Tail beyond the valid count is
// padded with 0 keys in LDS (keys buffer itself is not zeroed).
__global__ void __launch_bounds__(1024) k_sort(unsigned long long* __restrict__ keys,
                                               const unsigned* __restrict__ selcnt) {
    __shared__ unsigned long long s[CAP2];
    int img = blockIdx.x;
    unsigned cnt = selcnt[img * 64];
    if (cnt > CAP2) cnt = CAP2;
    unsigned long long* g = keys + (size_t)img * CAP2;
    for (int i = threadIdx.x; i < CAP2; i += 1024)
        s[i] = (i < (int)cnt) ? g[i] : 0ULL;
    __syncthreads();
    for (int k2 = 2; k2 <= CAP2; k2 <<= 1) {
        for (int j = k2 >> 1; j > 0; j >>= 1) {
            for (int i = threadIdx.x; i < CAP2; i += 1024) {
                int ixj = i ^ j;
                if (ixj > i) {
                    unsigned long long a = s[i], b = s[ixj];
                    bool up = ((i & k2) == 0);
                    if (up ? (a < b) : (a > b)) { s[i] = b; s[ixj] = a; }
                }
            }
            __syncthreads();
        }
    }
    for (int i = threadIdx.x; i < PRE; i += 1024) g[i] = s[i];
}

// K7: decode boxes (f64), clip, MIN_SIZE filter, sigmoid score.
// Writes f64 boxes (exact path) AND f32 boxes (screen path).
__global__ void k_decode(const float* __restrict__ anchors, const float* __restrict__ br,
                         const unsigned long long* __restrict__ keys,
                         double* __restrict__ boxes, float4* __restrict__ boxesf,
                         float* __restrict__ scores, unsigned* __restrict__ negmask) {
    int g = blockIdx.x * blockDim.x + threadIdx.x;
    if (g >= NIMG * PRE) return;
    int img = g / PRE, r = g % PRE;
    unsigned long long key = keys[(size_t)img * CAP2 + r];
    unsigned m = (unsigned)(key >> 32);
    unsigned idx = ~(unsigned)key;
    unsigned u = (m & 0x80000000u) ? (m ^ 0x80000000u) : ~m;
    float x = __uint_as_float(u);
    double sc = 1.0 / (1.0 + exp(-(double)x));
    int a = idx % 3;
    int hw = idx / 3;
    const float* anc = anchors + ((size_t)img * AHW + idx) * 4;
    double ax1 = anc[0], ay1 = anc[1], ax2 = anc[2], ay2 = anc[3];
    double aw = ax2 - ax1 + 1.0, ah = ay2 - ay1 + 1.0;
    double cx = ax1 + 0.5 * aw, cy = ay1 + 0.5 * ah;
    const float* bp = br + (size_t)img * 12 * HW + (size_t)a * 4 * HW + hw;
    double dx = bp[0];
    double dy = bp[(size_t)HW];
    double dw = bp[(size_t)2 * HW];
    double dh = bp[(size_t)3 * HW];
    const double CLIPV = 4.135166556742356; // log(1000/16)
    dw = fmin(dw, CLIPV); dh = fmin(dh, CLIPV);
    double pcx = dx * aw + cx, pcy = dy * ah + cy;
    double pw = exp(dw) * aw, ph = exp(dh) * ah;
    double x1 = pcx - 0.5 * pw, y1 = pcy - 0.5 * ph;
    double x2 = pcx + 0.5 * pw - 1.0, y2 = pcy + 0.5 * ph - 1.0;
    x1 = fmin(fmax(x1, 0.0), 1023.0);
    y1 = fmin(fmax(y1, 0.0), 1023.0);
    x2 = fmin(fmax(x2, 0.0), 1023.0);
    y2 = fmin(fmax(y2, 0.0), 1023.0);
    bool keep = (x2 - x1 + 1.0 >= 0.0) && (y2 - y1 + 1.0 >= 0.0);
    double* bo = boxes + ((size_t)img * PRE + r) * 4;
    bo[0] = x1; bo[1] = y1; bo[2] = x2; bo[3] = y2;
    float4 bf;
    bf.x = (float)x1; bf.y = (float)y1; bf.z = (float)x2; bf.w = (float)y2;
    boxesf[(size_t)img * PRE + r] = bf;
    scores[img * PRE + r] = keep ? (float)sc : NEGF;
    if (!keep) atomicOr(&negmask[img * 64 + (r >> 5)], 1u << (r & 31));
}

// K8: upper-triangle IoU suppression bitmask, f32 screen + exact f64 fallback
// for boundary pairs. STRIDED row assignment (block bx owns rows bx, bx+63,
// bx+126, ...) so every block gets a uniform mix of cheap (high-r) and
// expensive (low-r) triangle rows -> balanced work across the grid.
// Screen: d = 1.7*inter - (0.7*ar + 0.7*aj), with 0.7*area precomputed in LDS.
__global__ void __launch_bounds__(256) k_mask(const float4* __restrict__ boxesf,
                                              const double* __restrict__ boxes,
                                              unsigned* __restrict__ mask) {
    __shared__ float sx1[PRE], sy1[PRE], sx2[PRE], sy2[PRE], sa7[PRE];
    int img = blockIdx.y;
    int tid = threadIdx.x;
    int wave = tid >> 6, t = tid & 63;
    const float4* fb = boxesf + (size_t)img * PRE;
    for (int i = tid; i < PRE; i += 256) {
        float4 b = fb[i];
        sx1[i] = b.x; sy1[i] = b.y; sx2[i] = b.z; sy2[i] = b.w;
        sa7[i] = 0.7f * ((b.z - b.x + 1.0f) * (b.w - b.y + 1.0f));
    }
    __syncthreads();
    const double* base64 = boxes + (size_t)img * PRE * 4;
    for (int rr = 0; rr < 8; ++rr) {
        int r = blockIdx.x + MBLK * (wave * 8 + rr);   // strided row map
        if (r >= PRE) break;
        float x1 = sx1[r], y1 = sy1[r], x2 = sx2[r], y2 = sy2[r];
        float a7r = sa7[r];
        int kmin = r >> 6;
        unsigned myw = 0;
        for (int k = kmin; k < 32; ++k) {
            int colr = 64 * k + t;
            int col = colr < PRE ? colr : PRE - 1;
            float iw = fminf(x2, sx2[col]) - fmaxf(x1, sx1[col]) + 1.0f;
            float ih = fminf(y2, sy2[col]) - fmaxf(y1, sy1[col]) + 1.0f;
            bool res = false, need = false;
            if (iw > -BW && ih > -BW) {
                float inter = iw * ih;
                float d = fmaf(1.7f, inter, -(a7r + sa7[col]));
                need = (iw < BW) | (ih < BW) | (fabsf(d) < BD);
                res = d > 0.0f;
            }
            if (need) {
                // exact reference-formula recompute in f64 (rare)
                const double* ri = base64 + (size_t)r * 4;
                const double* rj = base64 + (size_t)col * 4;
                double X1 = ri[0], Y1 = ri[1], X2 = ri[2], Y2 = ri[3];
                double bX1 = rj[0], bY1 = rj[1], bX2 = rj[2], bY2 = rj[3];
                double IW = fmin(X2, bX2) - fmax(X1, bX1) + 1.0;
                double IH = fmin(Y2, bY2) - fmax(Y1, bY1) + 1.0;
                IW = IW > 0.0 ? IW : 0.0;
                IH = IH > 0.0 ? IH : 0.0;
                double INTER = IW * IH;
                double AR = (X2 - X1 + 1.0) * (Y2 - Y1 + 1.0);
                double AJ = (bX2 - bX1 + 1.0) * (bY2 - bY1 + 1.0);
                double IOU = INTER / ((AR + AJ) - INTER);
                res = IOU > 0.7;
            }
            res = res && (colr < PRE);
            unsigned long long bb = __ballot(res);
            if (t == 2 * k) myw = (unsigned)bb;
            if (t == 2 * k + 1) myw = (unsigned)(bb >> 32);
        }
        mask[((size_t)img * MROWS + r) * 64 + t] = myw;
    }
}

// K9: sequential-scan greedy NMS, branchless scalar-mirror inner loop.
#define NMS_LOAD(B, G)                                          \
    _Pragma("unroll")                                           \
    for (int s = 0; s < 16; ++s) B[s] = mrow[((G) * 16 + s) * 64];

#define NMS_PROC(B, G, PAR) {                                   \
    int W = (G) >> 1;                                           \
    if ((PAR) == 0) s_cur = (unsigned)__builtin_amdgcn_readlane((int)sup, W); \
    _Pragma("unroll")                                           \
    for (int s = 0; s < 16; ++s) {                              \
        unsigned rb = (unsigned)__builtin_amdgcn_readlane((int)B[s], W); \
        unsigned bit = (s_cur >> (((PAR) << 4) + s)) & 1u;      \
        unsigned am = bit - 1u;  /* alive: ~0, dead: 0 */       \
        s_cur |= rb & am;                                       \
        s_pick |= am & (1u << (((PAR) << 4) + s));              \
        sup |= B[s] & am;                                       \
    }                                                           \
    if ((PAR) == 1) {                                           \
        pickedv = (t == W) ? (int)s_pick : pickedv;             \
        np += __builtin_popcount(s_pick);                       \
        s_pick = 0;                                             \
    }                                                           \
}

__global__ void __launch_bounds__(64) k_nms(const double* __restrict__ boxes,
                                            const float* __restrict__ scores,
                                            const unsigned* __restrict__ negmask,
                                            const unsigned* __restrict__ mask,
                                            float* __restrict__ out) {
    __shared__ int picks[POST];
    __shared__ unsigned wcnt[64];
    __shared__ int tot;
    int img = blockIdx.x;
    int t = threadIdx.x;
    unsigned sup = negmask[img * 64 + t];
    if (t == 62) sup |= 0xFFFF0000u;  // indices 2000..2015 invalid
    if (t == 63) sup = 0xFFFFFFFFu;   // indices 2016..2047 invalid
    const unsigned* mrow = mask + (size_t)img * MROWS * 64 + t;
    unsigned b0[16], b1[16], b2[16], b3[16];
    NMS_LOAD(b0, 0)
    NMS_LOAD(b1, 1)
    NMS_LOAD(b2, 2)
    NMS_LOAD(b3, 3)
    int np = 0;
    unsigned s_cur = 0, s_pick = 0;
    int pickedv = 0;
    // 125 groups of 16 rows (2000). Main loop: groups 0..123; epilogue: 124.
    for (int gg = 0; gg < 124; gg += 4) {
        NMS_PROC(b0, gg + 0, 0) NMS_LOAD(b0, gg + 4)
        NMS_PROC(b1, gg + 1, 1) NMS_LOAD(b1, gg + 5)
        NMS_PROC(b2, gg + 2, 0) NMS_LOAD(b2, gg + 6)
        NMS_PROC(b3, gg + 3, 1) NMS_LOAD(b3, gg + 7)   // max load group 127 < MROWS/16
        if (np >= POST) break;
    }
    if (np < POST) {
        NMS_PROC(b0, 124, 0)   // jj 1984..1999, word 62 low half
        pickedv = (t == 62) ? (int)s_pick : pickedv;
        np += __builtin_popcount(s_pick);
    }
    // epilogue: materialize picks[] from the bitmap (lane W holds word W)
    wcnt[t] = (unsigned)__builtin_popcount((unsigned)pickedv);
    __syncthreads();
    int pre = 0;
    for (int i = 0; i < t; ++i) pre += (int)wcnt[i];
    if (t == 63) tot = pre + (int)wcnt[63];
    __syncthreads();
    unsigned pw = (unsigned)pickedv;
    int rank = pre;
    while (pw) {
        int b = __ffs(pw) - 1;
        pw &= pw - 1;
        if (rank < POST) picks[rank] = t * 32 + b;
        rank++;
    }
    __syncthreads();
    int np_final = tot > POST ? POST : tot;
    float* ob = out + (size_t)img * POST * 4;
    float* os = out + (size_t)NIMG * POST * 4 + (size_t)img * POST;
    for (int k = t; k < POST; k += 64) {
        if (k < np_final) {
            int p = picks[k];
            const double* bp = boxes + ((size_t)img * PRE + p) * 4;
            ob[k * 4 + 0] = (float)bp[0];
            ob[k * 4 + 1] = (float)bp[1];
            ob[k * 4 + 2] = (float)bp[2];
            ob[k * 4 + 3] = (float)bp[3];
            os[k] = scores[img * PRE + p];
        } else {
            ob[k * 4 + 0] = 0.0f; ob[k * 4 + 1] = 0.0f;
            ob[k * 4 + 2] = 0.0f; ob[k * 4 + 3] = 0.0f;
            os[k] = NEGF;
        }
    }
}

extern "C" void kernel_launch(void* const* d_in, const int* in_sizes, int n_in,
                              void* d_out, int out_size, void* d_ws, size_t ws_size,
                              hipStream_t stream) {
    const float* anchors = (const float*)d_in[0];
    const float4* obj4 = (const float4*)d_in[1];
    const float* br = (const float*)d_in[2];
    float* out = (float*)d_out;

    char* ws = (char*)d_ws;
    size_t off = 0;
    auto alloc = [&](size_t bytes) {
        void* p = ws + off;
        off = (off + bytes + 255) & ~(size_t)255;
        return p;
    };
    // zero-initialized region (single fused memset): hist..negmask
    unsigned* hist = (unsigned*)alloc((size_t)NIMG * NBUCKET * 4);
    unsigned* hist2 = (unsigned*)alloc((size_t)NIMG * NBUCKET * 4);
    unsigned* bsel = (unsigned*)alloc(NIMG * 4);
    unsigned* cntAbove = (unsigned*)alloc(NIMG * 4);
    unsigned* thr32 = (unsigned*)alloc(NIMG * 4);
    unsigned* selcnt = (unsigned*)alloc((size_t)NIMG * 64 * 4);      // one cache line per image
    unsigned* negmask = (unsigned*)alloc((size_t)NIMG * 64 * 4);
    size_t zero_bytes = off;
    // non-zeroed buffers
    unsigned long long* keys = (unsigned long long*)alloc((size_t)NIMG * CAP2 * 8);
    double* boxes = (double*)alloc((size_t)NIMG * PRE * 4 * 8);
    float4* boxesf = (float4*)alloc((size_t)NIMG * PRE * 16);
    float* scores = (float*)alloc((size_t)NIMG * PRE * 4);
    unsigned* mask = (unsigned*)alloc((size_t)NIMG * MROWS * 64 * 4);

    hipMemsetAsync(hist, 0, zero_bytes, stream);

    k_hist<<<dim3(16, NIMG), 256, 0, stream>>>(obj4, hist);
    k_thresh<<<NIMG, 256, 0, stream>>>(hist, bsel, cntAbove);
    k_hist2<<<dim3(16, NIMG), 256, 0, stream>>>(obj4, bsel, hist2);
    k_thresh2<<<NIMG, 256, 0, stream>>>(hist2, bsel, cntAbove, thr32);
    k_compact<<<dim3(64, NIMG), 256, 0, stream>>>(obj4, thr32, selcnt, keys);
    k_sort<<<NIMG, 1024, 0, stream>>>(keys, selcnt);
    k_decode<<<(NIMG * PRE + 255) / 256, 256, 0, stream>>>(anchors, br, keys, boxes, boxesf, scores, negmask);
    k_mask<<<dim3(MBLK, NIMG), 256, 0, stream>>>(boxesf, boxes, mask);
    k_nms<<<NIMG, 64, 0, stream>>>(boxes, scores, negmask, mask, out);
}

// Round 10
// 160.313 us; speedup vs baseline: 9.3039x; 1.1357x over previous
//
#include <hip/hip_runtime.h>
#include <math.h>

#define NIMG 16
#define A 3
#define HW 65536
#define AHW 196608
#define PRE 2000
#define POST 1000
#define CAP2 2048
#define MROWS 2048
#define NBUCKET 2048
#define NEGF (-1e30f)
#define LBUF 256
#define BW 0.01f
#define BD 4.0f
#define MBLK 64

__device__ __forceinline__ unsigned mapf(float x) {
    unsigned u = __float_as_uint(x);
    return (u & 0x80000000u) ? ~u : (u | 0x80000000u);
}

// K1: per-image histogram of top 11 bits of monotone-mapped objectness (float4 loads)
__global__ void __launch_bounds__(256) k_hist(const float4* __restrict__ obj4,
                                              unsigned* __restrict__ hist) {
    __shared__ unsigned lh[NBUCKET];
    int img = blockIdx.y;
    for (int i = threadIdx.x; i < NBUCKET; i += 256) lh[i] = 0;
    __syncthreads();
    const float4* p = obj4 + (size_t)img * (AHW / 4);
    int stride = gridDim.x * 256;
    for (int v = blockIdx.x * 256 + threadIdx.x; v < AHW / 4; v += stride) {
        float4 f = p[v];
        atomicAdd(&lh[mapf(f.x) >> 21], 1u);
        atomicAdd(&lh[mapf(f.y) >> 21], 1u);
        atomicAdd(&lh[mapf(f.z) >> 21], 1u);
        atomicAdd(&lh[mapf(f.w) >> 21], 1u);
    }
    __syncthreads();
    unsigned* gh = hist + img * NBUCKET;
    for (int i = threadIdx.x; i < NBUCKET; i += 256)
        if (lh[i]) atomicAdd(&gh[i], lh[i]);
}

// K2: find coarse threshold bucket B per image; also count strictly above B
__global__ void __launch_bounds__(256) k_thresh(const unsigned* __restrict__ hist,
                                                unsigned* __restrict__ bsel,
                                                unsigned* __restrict__ cntAbove) {
    __shared__ unsigned part[256];
    int img = blockIdx.x;
    int t = threadIdx.x;
    const unsigned* gh = hist + img * NBUCKET;
    unsigned s = 0;
    for (int k = 0; k < 8; ++k) s += gh[t * 8 + k];
    part[t] = s;
    __syncthreads();
    if (t == 0) {
        unsigned cum = 0;
        int done = 0;
        for (int c = 255; c >= 0 && !done; --c) {
            if (cum + part[c] >= PRE) {
                for (int i = c * 8 + 7; i >= c * 8; --i) {
                    unsigned h = gh[i];
                    if (cum + h >= PRE) { bsel[img] = (unsigned)i; cntAbove[img] = cum; done = 1; break; }
                    cum += h;
                }
            } else {
                cum += part[c];
            }
        }
    }
}

// K3: histogram of next 11 bits within coarse bucket B (float4 loads)
__global__ void __launch_bounds__(256) k_hist2(const float4* __restrict__ obj4,
                                               const unsigned* __restrict__ bsel,
                                               unsigned* __restrict__ hist2) {
    __shared__ unsigned lh[NBUCKET];
    int img = blockIdx.y;
    unsigned B = bsel[img];
    for (int i = threadIdx.x; i < NBUCKET; i += 256) lh[i] = 0;
    __syncthreads();
    const float4* p = obj4 + (size_t)img * (AHW / 4);
    int stride = gridDim.x * 256;
    for (int v = blockIdx.x * 256 + threadIdx.x; v < AHW / 4; v += stride) {
        float4 f = p[v];
        unsigned m0 = mapf(f.x), m1 = mapf(f.y), m2 = mapf(f.z), m3 = mapf(f.w);
        if ((m0 >> 21) == B) atomicAdd(&lh[(m0 >> 10) & 0x7FF], 1u);
        if ((m1 >> 21) == B) atomicAdd(&lh[(m1 >> 10) & 0x7FF], 1u);
        if ((m2 >> 21) == B) atomicAdd(&lh[(m2 >> 10) & 0x7FF], 1u);
        if ((m3 >> 21) == B) atomicAdd(&lh[(m3 >> 10) & 0x7FF], 1u);
    }
    __syncthreads();
    unsigned* gh = hist2 + img * NBUCKET;
    for (int i = threadIdx.x; i < NBUCKET; i += 256)
        if (lh[i]) atomicAdd(&gh[i], lh[i]);
}

// K4: refine to 22-bit threshold
__global__ void __launch_bounds__(256) k_thresh2(const unsigned* __restrict__ hist2,
                                                 const unsigned* __restrict__ bsel,
                                                 const unsigned* __restrict__ cntAbove,
                                                 unsigned* __restrict__ thr32) {
    __shared__ unsigned part[256];
    int img = blockIdx.x;
    int t = threadIdx.x;
    const unsigned* gh = hist2 + img * NBUCKET;
    unsigned s = 0;
    for (int k = 0; k < 8; ++k) s += gh[t * 8 + k];
    part[t] = s;
    __syncthreads();
    if (t == 0) {
        unsigned cum = cntAbove[img];
        unsigned B = bsel[img];
        int done = 0;
        for (int c = 255; c >= 0 && !done; --c) {
            if (cum + part[c] >= PRE) {
                for (int i = c * 8 + 7; i >= c * 8; --i) {
                    unsigned h = gh[i];
                    if (cum + h >= PRE) { thr32[img] = (B << 21) | ((unsigned)i << 10); done = 1; break; }
                    cum += h;
                }
            } else {
                cum += part[c];
            }
        }
    }
}

// K5: compact candidates with m >= thr. Two-level: LDS staging + one global
// atomic per block (selcnt padded to a private cache line per image).
__global__ void __launch_bounds__(256) k_compact(const float4* __restrict__ obj4,
                                                 const unsigned* __restrict__ thr32,
                                                 unsigned* __restrict__ selcnt,
                                                 unsigned long long* __restrict__ keys) {
    __shared__ unsigned long long lbuf[LBUF];
    __shared__ unsigned lcnt, gbase;
    int img = blockIdx.y;
    unsigned thr = thr32[img];
    if (threadIdx.x == 0) lcnt = 0;
    __syncthreads();
    const float4* p = obj4 + (size_t)img * (AHW / 4);
    int v0 = blockIdx.x * 768;
    #pragma unroll
    for (int it = 0; it < 3; ++it) {
        int v = v0 + it * 256 + threadIdx.x;
        float4 f = p[v];
        int jb = v * 4;
        #pragma unroll
        for (int k = 0; k < 4; ++k) {
            float x = k == 0 ? f.x : (k == 1 ? f.y : (k == 2 ? f.z : f.w));
            unsigned m = mapf(x);
            if (m >= thr) {
                int j = jb + k;
                int a = j >> 16;
                int hw = j & 65535;
                unsigned idx = (unsigned)(hw * A + a);
                unsigned pos = atomicAdd(&lcnt, 1u);
                if (pos < LBUF)
                    lbuf[pos] = ((unsigned long long)m << 32) | (unsigned)(~idx);
            }
        }
    }
    __syncthreads();
    unsigned n = lcnt > LBUF ? LBUF : lcnt;
    if (threadIdx.x == 0) gbase = atomicAdd(&selcnt[img * 64], n);
    __syncthreads();
    if (threadIdx.x < n) {
        unsigned pos = gbase + threadIdx.x;
        if (pos < CAP2)
            keys[(size_t)img * CAP2 + pos] = lbuf[threadIdx.x];
    }
}

// K6: per-image bitonic sort, descending. Tail beyond the valid count is
// padded with 0 keys in LDS (keys buffer itself is not zeroed).
__global__ void __launch_bounds__(1024) k_sort(unsigned long long* __restrict__ keys,
                                               const unsigned* __restrict__ selcnt) {
    __shared__ unsigned long long s[CAP2];
    int img = blockIdx.x;
    unsigned cnt = selcnt[img * 64];
    if (cnt > CAP2) cnt = CAP2;
    unsigned long long* g = keys + (size_t)img * CAP2;
    for (int i = threadIdx.x; i < CAP2; i += 1024)
        s[i] = (i < (int)cnt) ? g[i] : 0ULL;
    __syncthreads();
    for (int k2 = 2; k2 <= CAP2; k2 <<= 1) {
        for (int j = k2 >> 1; j > 0; j >>= 1) {
            for (int i = threadIdx.x; i < CAP2; i += 1024) {
                int ixj = i ^ j;
                if (ixj > i) {
                    unsigned long long a = s[i], b = s[ixj];
                    bool up = ((i & k2) == 0);
                    if (up ? (a < b) : (a > b)) { s[i] = b; s[ixj] = a; }
                }
            }
            __syncthreads();
        }
    }
    for (int i = threadIdx.x; i < PRE; i += 1024) g[i] = s[i];
}

// K7: decode boxes (f64), clip, MIN_SIZE filter, sigmoid score.
// Writes f64 boxes (exact path) AND f32 boxes (screen path).
__global__ void k_decode(const float* __restrict__ anchors, const float* __restrict__ br,
                         const unsigned long long* __restrict__ keys,
                         double* __restrict__ boxes, float4* __restrict__ boxesf,
                         float* __restrict__ scores, unsigned* __restrict__ negmask) {
    int g = blockIdx.x * blockDim.x + threadIdx.x;
    if (g >= NIMG * PRE) return;
    int img = g / PRE, r = g % PRE;
    unsigned long long key = keys[(size_t)img * CAP2 + r];
    unsigned m = (unsigned)(key >> 32);
    unsigned idx = ~(unsigned)key;
    unsigned u = (m & 0x80000000u) ? (m ^ 0x80000000u) : ~m;
    float x = __uint_as_float(u);
    double sc = 1.0 / (1.0 + exp(-(double)x));
    int a = idx % 3;
    int hw = idx / 3;
    const float* anc = anchors + ((size_t)img * AHW + idx) * 4;
    double ax1 = anc[0], ay1 = anc[1], ax2 = anc[2], ay2 = anc[3];
    double aw = ax2 - ax1 + 1.0, ah = ay2 - ay1 + 1.0;
    double cx = ax1 + 0.5 * aw, cy = ay1 + 0.5 * ah;
    const float* bp = br + (size_t)img * 12 * HW + (size_t)a * 4 * HW + hw;
    double dx = bp[0];
    double dy = bp[(size_t)HW];
    double dw = bp[(size_t)2 * HW];
    double dh = bp[(size_t)3 * HW];
    const double CLIPV = 4.135166556742356; // log(1000/16)
    dw = fmin(dw, CLIPV); dh = fmin(dh, CLIPV);
    double pcx = dx * aw + cx, pcy = dy * ah + cy;
    double pw = exp(dw) * aw, ph = exp(dh) * ah;
    double x1 = pcx - 0.5 * pw, y1 = pcy - 0.5 * ph;
    double x2 = pcx + 0.5 * pw - 1.0, y2 = pcy + 0.5 * ph - 1.0;
    x1 = fmin(fmax(x1, 0.0), 1023.0);
    y1 = fmin(fmax(y1, 0.0), 1023.0);
    x2 = fmin(fmax(x2, 0.0), 1023.0);
    y2 = fmin(fmax(y2, 0.0), 1023.0);
    bool keep = (x2 - x1 + 1.0 >= 0.0) && (y2 - y1 + 1.0 >= 0.0);
    double* bo = boxes + ((size_t)img * PRE + r) * 4;
    bo[0] = x1; bo[1] = y1; bo[2] = x2; bo[3] = y2;
    float4 bf;
    bf.x = (float)x1; bf.y = (float)y1; bf.z = (float)x2; bf.w = (float)y2;
    boxesf[(size_t)img * PRE + r] = bf;
    scores[img * PRE + r] = keep ? (float)sc : NEGF;
    if (!keep) atomicOr(&negmask[img * 64 + (r >> 5)], 1u << (r & 31));
}

// K8: upper-triangle IoU suppression bitmask, f32 screen + exact f64 fallback
// for boundary pairs. LDS packed as float2 pairs + 0.7*area, PADDED to 2048
// with degenerate sentinel boxes (iw ~ -2e8) so the inner loop has no col<PRE
// clamp and `need` is naturally false for pads. Strided row map (block bx owns
// rows bx + 64*widx) for balance; 64 blocks/img x 40960B LDS -> 4 blocks/CU.
__global__ void __launch_bounds__(256) k_mask(const float4* __restrict__ boxesf,
                                              const double* __restrict__ boxes,
                                              unsigned* __restrict__ mask) {
    __shared__ float2 sxy1[MROWS], sxy2[MROWS];
    __shared__ float sa7[MROWS];
    int img = blockIdx.y;
    int tid = threadIdx.x;
    int wave = tid >> 6, t = tid & 63;
    const float4* fb = boxesf + (size_t)img * PRE;
    for (int i = tid; i < MROWS; i += 256) {
        float4 b;
        if (i < PRE) {
            b = fb[i];
        } else {
            b.x = 1e8f; b.y = 1e8f; b.z = -1e8f; b.w = -1e8f;  // sentinel: never overlaps
        }
        sxy1[i] = make_float2(b.x, b.y);
        sxy2[i] = make_float2(b.z, b.w);
        sa7[i] = 0.7f * ((b.z - b.x + 1.0f) * (b.w - b.y + 1.0f));
    }
    __syncthreads();
    const double* base64 = boxes + (size_t)img * PRE * 4;
    for (int rr = 0; rr < 8; ++rr) {
        int r = blockIdx.x + MBLK * (rr * 4 + wave);   // strided row map, monotone in rr
        if (r >= PRE) break;
        float2 p1 = sxy1[r], p2 = sxy2[r];
        float a7r = sa7[r];
        int kmin = r >> 6;
        unsigned myw = 0;
        for (int k = kmin; k < 32; ++k) {
            int col = 64 * k + t;
            float2 q1 = sxy1[col], q2 = sxy2[col];
            float iw = fminf(p2.x, q2.x) - fmaxf(p1.x, q1.x) + 1.0f;
            float ih = fminf(p2.y, q2.y) - fmaxf(p1.y, q1.y) + 1.0f;
            bool res = false, need = false;
            if (iw > -BW && ih > -BW) {
                float inter = iw * ih;
                float d = fmaf(1.7f, inter, -(a7r + sa7[col]));
                need = (iw < BW) | (ih < BW) | (fabsf(d) < BD);
                res = d > 0.0f;
            }
            if (need) {
                // exact reference-formula recompute in f64 (rare; col < PRE
                // guaranteed: sentinel pads can never set `need`)
                const double* ri = base64 + (size_t)r * 4;
                const double* rj = base64 + (size_t)col * 4;
                double X1 = ri[0], Y1 = ri[1], X2 = ri[2], Y2 = ri[3];
                double bX1 = rj[0], bY1 = rj[1], bX2 = rj[2], bY2 = rj[3];
                double IW = fmin(X2, bX2) - fmax(X1, bX1) + 1.0;
                double IH = fmin(Y2, bY2) - fmax(Y1, bY1) + 1.0;
                IW = IW > 0.0 ? IW : 0.0;
                IH = IH > 0.0 ? IH : 0.0;
                double INTER = IW * IH;
                double AR = (X2 - X1 + 1.0) * (Y2 - Y1 + 1.0);
                double AJ = (bX2 - bX1 + 1.0) * (bY2 - bY1 + 1.0);
                double IOU = INTER / ((AR + AJ) - INTER);
                res = IOU > 0.7;
            }
            unsigned long long bb = __ballot(res);
            if (t == 2 * k) myw = (unsigned)bb;
            if (t == 2 * k + 1) myw = (unsigned)(bb >> 32);
        }
        mask[((size_t)img * MROWS + r) * 64 + t] = myw;
    }
}

// K9: sequential-scan greedy NMS, branchless scalar-mirror inner loop.
#define NMS_LOAD(B, G)                                          \
    _Pragma("unroll")                                           \
    for (int s = 0; s < 16; ++s) B[s] = mrow[((G) * 16 + s) * 64];

#define NMS_PROC(B, G, PAR) {                                   \
    int W = (G) >> 1;                                           \
    if ((PAR) == 0) s_cur = (unsigned)__builtin_amdgcn_readlane((int)sup, W); \
    _Pragma("unroll")                                           \
    for (int s = 0; s < 16; ++s) {                              \
        unsigned rb = (unsigned)__builtin_amdgcn_readlane((int)B[s], W); \
        unsigned bit = (s_cur >> (((PAR) << 4) + s)) & 1u;      \
        unsigned am = bit - 1u;  /* alive: ~0, dead: 0 */       \
        s_cur |= rb & am;                                       \
        s_pick |= am & (1u << (((PAR) << 4) + s));              \
        sup |= B[s] & am;                                       \
    }                                                           \
    if ((PAR) == 1) {                                           \
        pickedv = (t == W) ? (int)s_pick : pickedv;             \
        np += __builtin_popcount(s_pick);                       \
        s_pick = 0;                                             \
    }                                                           \
}

__global__ void __launch_bounds__(64) k_nms(const double* __restrict__ boxes,
                                            const float* __restrict__ scores,
                                            const unsigned* __restrict__ negmask,
                                            const unsigned* __restrict__ mask,
                                            float* __restrict__ out) {
    __shared__ int picks[POST];
    __shared__ unsigned wcnt[64];
    __shared__ int tot;
    int img = blockIdx.x;
    int t = threadIdx.x;
    unsigned sup = negmask[img * 64 + t];
    if (t == 62) sup |= 0xFFFF0000u;  // indices 2000..2015 invalid
    if (t == 63) sup = 0xFFFFFFFFu;   // indices 2016..2047 invalid
    const unsigned* mrow = mask + (size_t)img * MROWS * 64 + t;
    unsigned b0[16], b1[16], b2[16], b3[16];
    NMS_LOAD(b0, 0)
    NMS_LOAD(b1, 1)
    NMS_LOAD(b2, 2)
    NMS_LOAD(b3, 3)
    int np = 0;
    unsigned s_cur = 0, s_pick = 0;
    int pickedv = 0;
    // 125 groups of 16 rows (2000). Main loop: groups 0..123; epilogue: 124.
    for (int gg = 0; gg < 124; gg += 4) {
        NMS_PROC(b0, gg + 0, 0) NMS_LOAD(b0, gg + 4)
        NMS_PROC(b1, gg + 1, 1) NMS_LOAD(b1, gg + 5)
        NMS_PROC(b2, gg + 2, 0) NMS_LOAD(b2, gg + 6)
        NMS_PROC(b3, gg + 3, 1) NMS_LOAD(b3, gg + 7)   // max load group 127 < MROWS/16
        if (np >= POST) break;
    }
    if (np < POST) {
        NMS_PROC(b0, 124, 0)   // jj 1984..1999, word 62 low half
        pickedv = (t == 62) ? (int)s_pick : pickedv;
        np += __builtin_popcount(s_pick);
    }
    // epilogue: materialize picks[] from the bitmap (lane W holds word W)
    wcnt[t] = (unsigned)__builtin_popcount((unsigned)pickedv);
    __syncthreads();
    int pre = 0;
    for (int i = 0; i < t; ++i) pre += (int)wcnt[i];
    if (t == 63) tot = pre + (int)wcnt[63];
    __syncthreads();
    unsigned pw = (unsigned)pickedv;
    int rank = pre;
    while (pw) {
        int b = __ffs(pw) - 1;
        pw &= pw - 1;
        if (rank < POST) picks[rank] = t * 32 + b;
        rank++;
    }
    __syncthreads();
    int np_final = tot > POST ? POST : tot;
    float* ob = out + (size_t)img * POST * 4;
    float* os = out + (size_t)NIMG * POST * 4 + (size_t)img * POST;
    for (int k = t; k < POST; k += 64) {
        if (k < np_final) {
            int p = picks[k];
            const double* bp = boxes + ((size_t)img * PRE + p) * 4;
            ob[k * 4 + 0] = (float)bp[0];
            ob[k * 4 + 1] = (float)bp[1];
            ob[k * 4 + 2] = (float)bp[2];
            ob[k * 4 + 3] = (float)bp[3];
            os[k] = scores[img * PRE + p];
        } else {
            ob[k * 4 + 0] = 0.0f; ob[k * 4 + 1] = 0.0f;
            ob[k * 4 + 2] = 0.0f; ob[k * 4 + 3] = 0.0f;
            os[k] = NEGF;
        }
    }
}

extern "C" void kernel_launch(void* const* d_in, const int* in_sizes, int n_in,
                              void* d_out, int out_size, void* d_ws, size_t ws_size,
                              hipStream_t stream) {
    const float* anchors = (const float*)d_in[0];
    const float4* obj4 = (const float4*)d_in[1];
    const float* br = (const float*)d_in[2];
    float* out = (float*)d_out;

    char* ws = (char*)d_ws;
    size_t off = 0;
    auto alloc = [&](size_t bytes) {
        void* p = ws + off;
        off = (off + bytes + 255) & ~(size_t)255;
        return p;
    };
    // zero-initialized region (single fused memset): hist..negmask
    unsigned* hist = (unsigned*)alloc((size_t)NIMG * NBUCKET * 4);
    unsigned* hist2 = (unsigned*)alloc((size_t)NIMG * NBUCKET * 4);
    unsigned* bsel = (unsigned*)alloc(NIMG * 4);
    unsigned* cntAbove = (unsigned*)alloc(NIMG * 4);
    unsigned* thr32 = (unsigned*)alloc(NIMG * 4);
    unsigned* selcnt = (unsigned*)alloc((size_t)NIMG * 64 * 4);      // one cache line per image
    unsigned* negmask = (unsigned*)alloc((size_t)NIMG * 64 * 4);
    size_t zero_bytes = off;
    // non-zeroed buffers
    unsigned long long* keys = (unsigned long long*)alloc((size_t)NIMG * CAP2 * 8);
    double* boxes = (double*)alloc((size_t)NIMG * PRE * 4 * 8);
    float4* boxesf = (float4*)alloc((size_t)NIMG * PRE * 16);
    float* scores = (float*)alloc((size_t)NIMG * PRE * 4);
    unsigned* mask = (unsigned*)alloc((size_t)NIMG * MROWS * 64 * 4);

    hipMemsetAsync(hist, 0, zero_bytes, stream);

    k_hist<<<dim3(64, NIMG), 256, 0, stream>>>(obj4, hist);
    k_thresh<<<NIMG, 256, 0, stream>>>(hist, bsel, cntAbove);
    k_hist2<<<dim3(64, NIMG), 256, 0, stream>>>(obj4, bsel, hist2);
    k_thresh2<<<NIMG, 256, 0, stream>>>(hist2, bsel, cntAbove, thr32);
    k_compact<<<dim3(64, NIMG), 256, 0, stream>>>(obj4, thr32, selcnt, keys);
    k_sort<<<NIMG, 1024, 0, stream>>>(keys, selcnt);
    k_decode<<<(NIMG * PRE + 255) / 256, 256, 0, stream>>>(anchors, br, keys, boxes, boxesf, scores, negmask);
    k_mask<<<dim3(MBLK, NIMG), 256, 0, stream>>>(boxesf, boxes, mask);
    k_nms<<<NIMG, 64, 0, stream>>>(boxes, scores, negmask, mask, out);
}